// Round 6
// baseline (339.240 us; speedup 1.0000x reference)
//
#include <hip/hip_runtime.h>
#include <hip/hip_bf16.h>
#include <stdint.h>

// Transformer-XL relative MHA on MI355X (gfx950), bf16 MFMA pipeline.
// B=2, Q=1024, M=1024, D=1024, H=16, DH=64, K=2048.
// Buffers are fp32 (reference dtypes); checker threshold 1.38e-3.
// Evidence log:
//  - async global_load_lds GEMM staging verified (R5==R6 identity, R7/R8 pass).
//  - R5 failure isolated to bpermute block-selection (banned).
//  - R9/R10: K-split regressed; occupancy pinned ~2 blocks/CU (grid-limited).
//  - R10 verified: compact-U layout, hvT pre-transpose (kept).
//  - R11: register-prefetch software pipelining in the attn K-loop.
//  - R12: qt complement-remap; setprio; dead-tail skip. 305->287.
//  - R13: rolling R window + single barrier + fused qkvr GEMM. 287->272 but
//    k_attn only 83->81.4; FETCH unchanged => barrier/staging theory WRONG.
//    Post-mortem: LDS pipe is saturated (~710 cy/wave-iter of LDS ops x8
//    waves ~= measured iter time; MFMA/VALU/HBM all idle).
//  - R14 (3rd submit; R4/R5 leases timed out): REGISTER-DIRECT K/V/R. Fragment
//    addresses are wave-invariant (K/V) so LDS staging only deduped reads the
//    L1/L2 already dedupes. K/V/R fragments now load straight from global
//    (same indexing, stride 64/2048); LDS keeps only the per-wave U slab
//    (shift+transpose, strides 84/76 verified bank-optimal). ALL barriers
//    removed (no shared LDS). K register-double-buffered; R/V issued early.
//    Out-of-range R rows (j>=2048) only reach masked k (j=1023+k-q<=2047
//    unmasked); p forced 0 by select => garbage never enters Ps/lp.

typedef __bf16 bf16;
typedef __bf16 bf16x2 __attribute__((ext_vector_type(2)));
typedef __bf16 bf16x4 __attribute__((ext_vector_type(4)));
typedef __bf16 bf16x8 __attribute__((ext_vector_type(8)));
typedef float  f32x4  __attribute__((ext_vector_type(4)));

// ---------------------------------------------------------------- async copy
__device__ __forceinline__ void async_copy16(void* lds, const void* g) {
    auto gp = (const __attribute__((address_space(1))) void*)(uintptr_t)g;
    auto lp = (__attribute__((address_space(3))) void*)(uint32_t)(uintptr_t)lds;
    __builtin_amdgcn_global_load_lds(gp, lp, 16, 0, 0);
}

// ------------------------------------------------------- 128x128 GEMM core
// C[128,128] = A[m0:+128, :Kd] * Bt[n0:+128, :Kd]^T   (both bf16, K contiguous)
// acc[rb][cb] C-layout: row = m0 + wr + rb*16 + (lane>>4)*4 + reg,
//                       col = n0 + wc + cb*16 + (lane&15)
__device__ __forceinline__ void gemm128_core(
    const bf16* __restrict__ A, const bf16* __restrict__ Bt, const int Kd,
    const int m0, const int n0, bf16* As, bf16* Bs, f32x4 acc[4][4])
{
    const int tid  = threadIdx.x;
    const int lane = tid & 63;
    const int wave = tid >> 6;
    const int wr   = (wave >> 1) * 64;
    const int wc   = (wave & 1) * 64;
    const int lr   = lane & 15;
    const int q4   = lane >> 4;

#pragma unroll
    for (int i = 0; i < 4; ++i)
#pragma unroll
        for (int j = 0; j < 4; ++j) {
            acc[i][j][0] = 0.f; acc[i][j][1] = 0.f; acc[i][j][2] = 0.f; acc[i][j][3] = 0.f;
        }

    for (int k0 = 0; k0 < Kd; k0 += 32) {
#pragma unroll
        for (int it = 0; it < 2; ++it) {
            const int cb0   = (it * 4 + wave) * 64;   // wave-uniform chunk base
            const int chunk = cb0 + lane;
            const int row   = chunk >> 2;
            const int cg    = (chunk & 3) * 8;
            async_copy16(As + cb0 * 8, A  + (size_t)(m0 + row) * Kd + k0 + cg);
            async_copy16(Bs + cb0 * 8, Bt + (size_t)(n0 + row) * Kd + k0 + cg);
        }
        __syncthreads();
        bf16x8 af[4], bfr[4];
#pragma unroll
        for (int rb = 0; rb < 4; ++rb)
            af[rb] = *(const bf16x8*)&As[(wr + rb * 16 + lr) * 32 + q4 * 8];
#pragma unroll
        for (int cb = 0; cb < 4; ++cb)
            bfr[cb] = *(const bf16x8*)&Bs[(wc + cb * 16 + lr) * 32 + q4 * 8];
#pragma unroll
        for (int rb = 0; rb < 4; ++rb)
#pragma unroll
            for (int cb = 0; cb < 4; ++cb)
                acc[rb][cb] = __builtin_amdgcn_mfma_f32_16x16x32_bf16(af[rb], bfr[cb], acc[rb][cb], 0, 0, 0);
        __syncthreads();
    }
}

// ------------------------------------------------------------- prep kernels
__global__ __launch_bounds__(256) void k_tcast(const float* __restrict__ in,
                                               bf16* __restrict__ out, int R, int C)
{
    __shared__ float t[32][33];
    const int c0 = blockIdx.x * 32, r0 = blockIdx.y * 32;
    const int lc = threadIdx.x & 31, lrow = threadIdx.x >> 5;
#pragma unroll
    for (int p = 0; p < 4; ++p)
        t[lrow + p * 8][lc] = in[(size_t)(r0 + lrow + p * 8) * C + c0 + lc];
    __syncthreads();
#pragma unroll
    for (int p = 0; p < 4; ++p)
        out[(size_t)(c0 + lrow + p * 8) * R + r0 + lc] = (bf16)t[lc][lrow + p * 8];
}

__global__ __launch_bounds__(256) void k_cast_cat(const float* __restrict__ mem,
                                                  const float* __restrict__ inp,
                                                  bf16* __restrict__ catb)
{
    const int e   = (blockIdx.x * 256 + threadIdx.x) * 4;
    const int row = e >> 10, dc = e & 1023;
    const int b   = row >> 11, k = row & 2047;
    const float* src = (k < 1024) ? mem + ((size_t)b * 1024 + k) * 1024 + dc
                                  : inp + ((size_t)b * 1024 + (k - 1024)) * 1024 + dc;
    float4 f = *(const float4*)src;
    bf16x4 o; o[0] = (bf16)f.x; o[1] = (bf16)f.y; o[2] = (bf16)f.z; o[3] = (bf16)f.w;
    *(bf16x4*)&catb[e] = o;
}

__global__ __launch_bounds__(256) void k_cast(const float* __restrict__ in,
                                              bf16* __restrict__ out)
{
    const int e = (blockIdx.x * 256 + threadIdx.x) * 4;
    float4 f = *(const float4*)(in + e);
    bf16x4 o; o[0] = (bf16)f.x; o[1] = (bf16)f.y; o[2] = (bf16)f.z; o[3] = (bf16)f.w;
    *(bf16x4*)&out[e] = o;
}

// ------------------------------------------------- fused QKV + R GEMM
// blockIdx.y in [0,24): QKV GEMM (catb @ Wqkvt), epilogue scatters q/k/v.
// blockIdx.y in [24,32): R GEMM (rb @ Wrt), epilogue writes hr.
// hv is written TRANSPOSED per head: hvT[bh][d][k]  (for direct Vt fragments)
__global__ __launch_bounds__(256) void k_gemm_qkvr(
    const bf16* __restrict__ catb, const bf16* __restrict__ Wqkvt,
    const float* __restrict__ b_qkv, const float* __restrict__ u, const float* __restrict__ v,
    const bf16* __restrict__ rb_, const bf16* __restrict__ Wrt,
    const float* __restrict__ b_r,
    bf16* __restrict__ hq_u, bf16* __restrict__ hq_v,
    bf16* __restrict__ hk, bf16* __restrict__ hvT, bf16* __restrict__ hr)
{
    __shared__ bf16 lds[2 * 128 * 32];
    f32x4 acc[4][4];
    const int m0 = blockIdx.x * 128;
    const int lane = threadIdx.x & 63, wave = threadIdx.x >> 6;
    const int wr = (wave >> 1) * 64, wc = (wave & 1) * 64;
    const int lr = lane & 15, q4 = lane >> 4;

    if (blockIdx.y < 24) {
        const int n0 = blockIdx.y * 128;
        gemm128_core(catb, Wqkvt, 1024, m0, n0, lds, lds + 128 * 32, acc);
#pragma unroll
        for (int rb = 0; rb < 4; ++rb) {
#pragma unroll
            for (int cb = 0; cb < 4; ++cb) {
                const int col  = n0 + wc + cb * 16 + lr;
                const int part = col >> 10;
                const int hd   = col & 1023;
                const int h    = hd >> 6, d = hd & 63;
                const float bcol = b_qkv[col];
#pragma unroll
                for (int r = 0; r < 4; ++r) {
                    const int row = m0 + wr + rb * 16 + q4 * 4 + r;
                    const int b   = row >> 11, k = row & 2047;
                    const float val = acc[rb][cb][r] + bcol;
                    if (part == 0) {
                        if (k >= 1024) {
                            const size_t o = (((size_t)(b * 16 + h)) * 1024 + (k - 1024)) * 64 + d;
                            hq_u[o] = (bf16)(val + u[hd]);
                            hq_v[o] = (bf16)(val + v[hd]);
                        }
                    } else if (part == 1) {
                        hvT[(((size_t)(b * 16 + h)) * 64 + d) * 2048 + k] = (bf16)val;
                    } else {
                        hk[(((size_t)(b * 16 + h)) * 2048 + k) * 64 + d] = (bf16)val;
                    }
                }
            }
        }
    } else {
        const int n0 = (blockIdx.y - 24) * 128;
        gemm128_core(rb_, Wrt, 1024, m0, n0, lds, lds + 128 * 32, acc);
#pragma unroll
        for (int rb = 0; rb < 4; ++rb) {
#pragma unroll
            for (int cb = 0; cb < 4; ++cb) {
                const int col = n0 + wc + cb * 16 + lr;
                const int h = col >> 6, d = col & 63;
                const float bcol = b_r[col];
#pragma unroll
                for (int r = 0; r < 4; ++r) {
                    const int row = m0 + wr + rb * 16 + q4 * 4 + r;
                    const int b = row >> 11, k = row & 2047;
                    hr[(((size_t)(b * 16 + h)) * 2048 + k) * 64 + d] = (bf16)(acc[rb][cb][r] + bcol);
                }
            }
        }
    }
}

// ---------------------------------------------------------------- out GEMM
__global__ __launch_bounds__(256) void k_gemm_out(
    const bf16* __restrict__ attn, const bf16* __restrict__ Wt,
    const float* __restrict__ bias, float* __restrict__ out)
{
    __shared__ bf16 lds[2 * 128 * 32];
    f32x4 acc[4][4];
    const int m0 = blockIdx.x * 128, n0 = blockIdx.y * 128;
    gemm128_core(attn, Wt, 1024, m0, n0, lds, lds + 128 * 32, acc);

    const int lane = threadIdx.x & 63, wave = threadIdx.x >> 6;
    const int wr = (wave >> 1) * 64, wc = (wave & 1) * 64;
    const int lr = lane & 15, q4 = lane >> 4;
#pragma unroll
    for (int rb = 0; rb < 4; ++rb) {
#pragma unroll
        for (int cb = 0; cb < 4; ++cb) {
            const int col = n0 + wc + cb * 16 + lr;
            const float bcol = bias[col];
#pragma unroll
            for (int r = 0; r < 4; ++r) {
                const int row = m0 + wr + rb * 16 + q4 * 4 + r;
                out[(size_t)row * 1024 + col] = acc[rb][cb][r] + bcol;
            }
        }
    }
}

// ------------------------- fused attention, register-direct, barrier-free
// One workgroup per (bh, 64-q tile), 64-key tiles. No online max (R8-verified).
// R14: K/V/R fragments load straight from global (wave-invariant addresses,
// L1/L2 dedupe what LDS staging deduped). LDS = per-wave U slab only.
// NO __syncthreads anywhere. K is register-double-buffered; R/V issued at
// iteration top (>=1 MFMA phase before first use).
__global__ __launch_bounds__(256, 2) void k_attn(
    const bf16* __restrict__ hq_u, const bf16* __restrict__ hq_v,
    const bf16* __restrict__ hk, const bf16* __restrict__ hvT,
    const bf16* __restrict__ hr, bf16* __restrict__ attn)
{
    __shared__ bf16 U[4][1344];        // per-wave: BD view [16][84] / Ps view [16][76]

    const int bh = blockIdx.y;
    // complement remap: linear block i and i+256 co-reside on a CU; pairing
    // qt with 15-qt makes their total work (17+qt)+(32-qt)=49 uniform.
    const int qt = (bh & 16) ? (15 - (int)blockIdx.x) : (int)blockIdx.x;
    const int q0 = qt * 64;
    const int tid = threadIdx.x, lane = tid & 63, wave = tid >> 6;
    const int lr = lane & 15, q4 = lane >> 4;
    bf16* Uw = &U[wave][0];

    const int nt    = 17 + qt;                // K-tiles for this q-tile
    const int m0c   = 15 - qt;                // base R-chunk index at t=0
    const int jbase = 3 - wave;               // per-wave BD band offset
    const size_t kvbase = (size_t)bh * 2048 * 64;

    // per-lane fragment base pointers (A/B-operand layout: row lr, cols q4*8)
    const bf16* Kp = hk  + kvbase + (size_t)lr * 64   + q4 * 8;
    const bf16* Vp = hvT + kvbase + (size_t)lr * 2048 + q4 * 8;
    const bf16* Rp = hr  + kvbase + (size_t)lr * 64   + q4 * 8;

    // Q fragments (A-operand layout: m = lane&15, k = (lane>>4)*8 + j)
    const size_t qrow = ((size_t)bh * 1024 + q0 + wave * 16 + lr) * 64;
    const bf16x8 qu0 = *(const bf16x8*)&hq_u[qrow + q4 * 8];
    const bf16x8 qu1 = *(const bf16x8*)&hq_u[qrow + 32 + q4 * 8];
    const bf16x8 qv0 = *(const bf16x8*)&hq_v[qrow + q4 * 8];
    const bf16x8 qv1 = *(const bf16x8*)&hq_v[qrow + 32 + q4 * 8];

    f32x4 Oacc[4];
#pragma unroll
    for (int i = 0; i < 4; ++i) { Oacc[i][0] = 0.f; Oacc[i][1] = 0.f; Oacc[i][2] = 0.f; Oacc[i][3] = 0.f; }
    float lp[4] = {0.f, 0.f, 0.f, 0.f};

    // current K fragments (double-buffered in registers)
    bf16x8 ka[4][2];
#pragma unroll
    for (int cb = 0; cb < 4; ++cb) {
        ka[cb][0] = *(const bf16x8*)(Kp + (size_t)(cb * 16) * 64);
        ka[cb][1] = *(const bf16x8*)(Kp + (size_t)(cb * 16) * 64 + 32);
    }

    for (int t = 0; t < nt; ++t) {
        const int k0 = t * 64;
        const int mt = m0c + t;
        const bool more = (t + 1 < nt);

        // ---- issue THIS tile's R band loads (used in BD, after AC)
        bf16x8 ra[5][2];
#pragma unroll
        for (int jbi = 0; jbi < 5; ++jbi) {
            const size_t rrow = (size_t)(mt * 64 + (jbase + jbi) * 16) * 64;
            ra[jbi][0] = *(const bf16x8*)(Rp + rrow);
            ra[jbi][1] = *(const bf16x8*)(Rp + rrow + 32);
        }
        // ---- issue THIS tile's V loads (used last, in PV)
        bf16x8 va[4][2];
#pragma unroll
        for (int db = 0; db < 4; ++db) {
            va[db][0] = *(const bf16x8*)(Vp + (size_t)(db * 16) * 2048 + k0);
            va[db][1] = *(const bf16x8*)(Vp + (size_t)(db * 16) * 2048 + k0 + 32);
        }
        // ---- prefetch NEXT tile's K
        bf16x8 kn[4][2];
        if (more) {
#pragma unroll
            for (int cb = 0; cb < 4; ++cb) {
                kn[cb][0] = *(const bf16x8*)(Kp + (size_t)(k0 + 64 + cb * 16) * 64);
                kn[cb][1] = *(const bf16x8*)(Kp + (size_t)(k0 + 64 + cb * 16) * 64 + 32);
            }
        }

        __builtin_amdgcn_s_setprio(1);
        // ---- AC = (hq+u) @ K^T  (ka resident from previous iteration)
        f32x4 S[4];
#pragma unroll
        for (int cb = 0; cb < 4; ++cb) {
            f32x4 z; z[0] = 0.f; z[1] = 0.f; z[2] = 0.f; z[3] = 0.f;
            z = __builtin_amdgcn_mfma_f32_16x16x32_bf16(qu0, ka[cb][0], z, 0, 0, 0);
            S[cb] = __builtin_amdgcn_mfma_f32_16x16x32_bf16(qu1, ka[cb][1], z, 0, 0, 0);
        }
        // ---- BD band -> compact LDS view (stride 84, col jbi*16+lr)
#pragma unroll
        for (int jbi = 0; jbi < 5; ++jbi) {
            f32x4 z; z[0] = 0.f; z[1] = 0.f; z[2] = 0.f; z[3] = 0.f;
            z = __builtin_amdgcn_mfma_f32_16x16x32_bf16(qv0, ra[jbi][0], z, 0, 0, 0);
            z = __builtin_amdgcn_mfma_f32_16x16x32_bf16(qv1, ra[jbi][1], z, 0, 0, 0);
#pragma unroll
            for (int r = 0; r < 4; ++r) Uw[(q4 * 4 + r) * 84 + jbi * 16 + lr] = (bf16)z[r];
        }

        // ---- read ALL shifted BD values into registers (before Ps writes:
        //      BD view (stride 84) and Ps view (stride 76) overlap in the slab)
        float bdv[4][4];
#pragma unroll
        for (int cb = 0; cb < 4; ++cb)
#pragma unroll
            for (int r = 0; r < 4; ++r) {
                const int tq = q4 * 4 + r;
                bdv[cb][r] = (float)Uw[tq * 84 + cb * 16 + lr + 15 - tq];
            }

        // ---- scores: mask, exp (no max), accumulate l, Ps write (stride 76)
#pragma unroll
        for (int cb = 0; cb < 4; ++cb) {
            const int k = k0 + cb * 16 + lr;
#pragma unroll
            for (int r = 0; r < 4; ++r) {
                const int q = q0 + wave * 16 + q4 * 4 + r;
                const float s = (S[cb][r] + bdv[cb][r]) * 0.125f;
                const float p = (k <= 1024 + q) ? __expf(s) : 0.f;
                lp[r] += p;
                Uw[(q4 * 4 + r) * 76 + cb * 16 + lr] = (bf16)p;   // Ps view
            }
        }

        // ---- PV: P (A-layout via Ps view) @ V (va from this iteration's loads)
        const bf16x8 pf0 = *(const bf16x8*)&Uw[lr * 76 + q4 * 8];
        const bf16x8 pf1 = *(const bf16x8*)&Uw[lr * 76 + 32 + q4 * 8];
#pragma unroll
        for (int db = 0; db < 4; ++db) {
            Oacc[db] = __builtin_amdgcn_mfma_f32_16x16x32_bf16(pf0, va[db][0], Oacc[db], 0, 0, 0);
            Oacc[db] = __builtin_amdgcn_mfma_f32_16x16x32_bf16(pf1, va[db][1], Oacc[db], 0, 0, 0);
        }
        __builtin_amdgcn_s_setprio(0);

        // ---- rotate K double-buffer (kn completed during this iteration)
        if (more) {
#pragma unroll
            for (int cb = 0; cb < 4; ++cb) {
                ka[cb][0] = kn[cb][0];
                ka[cb][1] = kn[cb][1];
            }
        }
    }

    // ---- 16-lane row-sum of l, normalize, write
#pragma unroll
    for (int off = 1; off < 16; off <<= 1)
#pragma unroll
        for (int r = 0; r < 4; ++r) lp[r] += __shfl_xor(lp[r], off, 64);

    const int b = bh >> 4, h = bh & 15;
#pragma unroll
    for (int r = 0; r < 4; ++r) {
        const float rl = 1.f / lp[r];
        const int q = q0 + wave * 16 + q4 * 4 + r;
#pragma unroll
        for (int db = 0; db < 4; ++db) {
            const int d = db * 16 + lr;
            attn[(((size_t)b * 1024 + q) * 16 + h) * 64 + d] = (bf16)(Oacc[db][r] * rl);
        }
    }
}

// ------------------------------------------------------------------ launch
extern "C" void kernel_launch(void* const* d_in, const int* in_sizes, int n_in,
                              void* d_out, int out_size, void* d_ws, size_t ws_size,
                              hipStream_t stream)
{
    const float* inputs = (const float*)d_in[0];
    const float* mem    = (const float*)d_in[1];
    const float* r      = (const float*)d_in[2];
    const float* W_qkv  = (const float*)d_in[3];
    const float* b_qkv  = (const float*)d_in[4];
    const float* W_r    = (const float*)d_in[5];
    const float* b_r    = (const float*)d_in[6];
    const float* W_o    = (const float*)d_in[7];
    const float* b_o    = (const float*)d_in[8];
    const float* u      = (const float*)d_in[9];
    const float* v      = (const float*)d_in[10];
    float* out = (float*)d_out;

    char* ws = (char*)d_ws;
    size_t off = 0;
    auto alloc = [&](size_t bytes) -> void* {
        void* p = ws + off;
        off += (bytes + 255) & ~(size_t)255;
        return p;
    };
    bf16* hq_u  = (bf16*)alloc(2ull * 16 * 1024 * 64 * 2);
    bf16* hq_v  = (bf16*)alloc(2ull * 16 * 1024 * 64 * 2);
    bf16* hk    = (bf16*)alloc(2ull * 16 * 2048 * 64 * 2);
    bf16* hvT   = (bf16*)alloc(2ull * 16 * 2048 * 64 * 2);
    bf16* hr    = (bf16*)alloc(2ull * 16 * 2048 * 64 * 2);
    bf16* attnb = (bf16*)alloc(2ull * 1024 * 1024 * 2);
    bf16* Wot   = (bf16*)alloc(1024ull * 1024 * 2);
    bf16* catb  = (bf16*)alloc(4096ull * 1024 * 2);
    bf16* rb    = (bf16*)alloc(4096ull * 1024 * 2);
    bf16* Wqkvt = (bf16*)alloc(3072ull * 1024 * 2);
    bf16* Wrt   = (bf16*)alloc(1024ull * 1024 * 2);

    k_tcast<<<dim3(96, 32), 256, 0, stream>>>(W_qkv, Wqkvt, 1024, 3072);
    k_tcast<<<dim3(32, 32), 256, 0, stream>>>(W_r, Wrt, 1024, 1024);
    k_tcast<<<dim3(32, 32), 256, 0, stream>>>(W_o, Wot, 1024, 1024);
    k_cast_cat<<<4096, 256, 0, stream>>>(mem, inputs, catb);
    k_cast<<<4096, 256, 0, stream>>>(r, rb);

    k_gemm_qkvr<<<dim3(32, 32), 256, 0, stream>>>(catb, Wqkvt, b_qkv, u, v,
                                                  rb, Wrt, b_r,
                                                  hq_u, hq_v, hk, hvT, hr);
    k_attn<<<dim3(16, 32), 256, 0, stream>>>(hq_u, hq_v, hk, hvT, hr, attnb);
    k_gemm_out<<<dim3(16, 8), 256, 0, stream>>>(attnb, Wot, b_o, out);
}

// Round 7
// 261.673 us; speedup vs baseline: 1.2964x; 1.2964x over previous
//
#include <hip/hip_runtime.h>
#include <hip/hip_bf16.h>
#include <stdint.h>

// Transformer-XL relative MHA on MI355X (gfx950), bf16 MFMA pipeline.
// B=2, Q=1024, M=1024, D=1024, H=16, DH=64, K=2048.
// Buffers are fp32 (reference dtypes); checker threshold 1.38e-3.
// Evidence log:
//  - async global_load_lds GEMM staging verified (R5==R6 identity, R7/R8 pass).
//  - R5 failure isolated to bpermute block-selection (banned).
//  - R9/R10: K-split regressed; occupancy pinned ~2 blocks/CU (grid-limited).
//  - R10 verified: compact-U layout, hvT pre-transpose (kept).
//  - R12: qt complement-remap; setprio; dead-tail skip. 305->287.
//  - R13: rolling R window + single barrier + fused qkvr GEMM. 287->272;
//    k_attn 81.4 us. LDS-pipe model: ~710 cy/wave-iter, U-slab scalars ~330.
//  - R14 REFUTED (153 us, MfmaUtil 5.5%, VGPR=100): register-direct K/V/R
//    made compiler sink loads to uses (serialized latency) and every fragment
//    load is a 16-cache-line gather. LDS staging = gather->coalesce converter.
//  - R15 (this): revert to R13 k_attn; vectorize BD writes via transposed
//    BDT view (stride 20, b64-aligned, bank-spread): 20 scalar ds_write_b16
//    -> 5 ds_write_b64 per wave-iter. Shifted reads unchanged in count.
//    Merge 5 prep launches into 2 (routing only).

typedef __bf16 bf16;
typedef __bf16 bf16x2 __attribute__((ext_vector_type(2)));
typedef __bf16 bf16x4 __attribute__((ext_vector_type(4)));
typedef __bf16 bf16x8 __attribute__((ext_vector_type(8)));
typedef float  f32x4  __attribute__((ext_vector_type(4)));

// ---------------------------------------------------------------- async copy
__device__ __forceinline__ void async_copy16(void* lds, const void* g) {
    auto gp = (const __attribute__((address_space(1))) void*)(uintptr_t)g;
    auto lp = (__attribute__((address_space(3))) void*)(uint32_t)(uintptr_t)lds;
    __builtin_amdgcn_global_load_lds(gp, lp, 16, 0, 0);
}

// ------------------------------------------------------- 128x128 GEMM core
__device__ __forceinline__ void gemm128_core(
    const bf16* __restrict__ A, const bf16* __restrict__ Bt, const int Kd,
    const int m0, const int n0, bf16* As, bf16* Bs, f32x4 acc[4][4])
{
    const int tid  = threadIdx.x;
    const int lane = tid & 63;
    const int wave = tid >> 6;
    const int wr   = (wave >> 1) * 64;
    const int wc   = (wave & 1) * 64;
    const int lr   = lane & 15;
    const int q4   = lane >> 4;

#pragma unroll
    for (int i = 0; i < 4; ++i)
#pragma unroll
        for (int j = 0; j < 4; ++j) {
            acc[i][j][0] = 0.f; acc[i][j][1] = 0.f; acc[i][j][2] = 0.f; acc[i][j][3] = 0.f;
        }

    for (int k0 = 0; k0 < Kd; k0 += 32) {
#pragma unroll
        for (int it = 0; it < 2; ++it) {
            const int cb0   = (it * 4 + wave) * 64;   // wave-uniform chunk base
            const int chunk = cb0 + lane;
            const int row   = chunk >> 2;
            const int cg    = (chunk & 3) * 8;
            async_copy16(As + cb0 * 8, A  + (size_t)(m0 + row) * Kd + k0 + cg);
            async_copy16(Bs + cb0 * 8, Bt + (size_t)(n0 + row) * Kd + k0 + cg);
        }
        __syncthreads();
        bf16x8 af[4], bfr[4];
#pragma unroll
        for (int rb = 0; rb < 4; ++rb)
            af[rb] = *(const bf16x8*)&As[(wr + rb * 16 + lr) * 32 + q4 * 8];
#pragma unroll
        for (int cb = 0; cb < 4; ++cb)
            bfr[cb] = *(const bf16x8*)&Bs[(wc + cb * 16 + lr) * 32 + q4 * 8];
#pragma unroll
        for (int rb = 0; rb < 4; ++rb)
#pragma unroll
            for (int cb = 0; cb < 4; ++cb)
                acc[rb][cb] = __builtin_amdgcn_mfma_f32_16x16x32_bf16(af[rb], bfr[cb], acc[rb][cb], 0, 0, 0);
        __syncthreads();
    }
}

// -------------------------------------------------- merged prep: weights
// 5120 blocks: [0,3072) Wqkv 1024x3072; [3072,4096) Wr; [4096,5120) Wo.
__global__ __launch_bounds__(256) void k_prep_w(
    const float* __restrict__ Wqkv, const float* __restrict__ Wr,
    const float* __restrict__ Wo,
    bf16* __restrict__ Wqkvt, bf16* __restrict__ Wrt, bf16* __restrict__ Wot)
{
    __shared__ float t[32][33];
    int id = blockIdx.x;
    const float* in; bf16* out; int C, bx, by;
    if (id < 3072)      { in = Wqkv; out = Wqkvt; C = 3072; bx = id % 96; by = id / 96; }
    else if (id < 4096) { id -= 3072; in = Wr; out = Wrt; C = 1024; bx = id & 31; by = id >> 5; }
    else                { id -= 4096; in = Wo; out = Wot; C = 1024; bx = id & 31; by = id >> 5; }
    const int R = 1024;
    const int c0 = bx * 32, r0 = by * 32;
    const int lc = threadIdx.x & 31, lrow = threadIdx.x >> 5;
#pragma unroll
    for (int p = 0; p < 4; ++p)
        t[lrow + p * 8][lc] = in[(size_t)(r0 + lrow + p * 8) * C + c0 + lc];
    __syncthreads();
#pragma unroll
    for (int p = 0; p < 4; ++p)
        out[(size_t)(c0 + lrow + p * 8) * R + r0 + lc] = (bf16)t[lc][lrow + p * 8];
}

// -------------------------------------------------- merged prep: activations
// 8192 blocks: [0,4096) cast_cat(mem,inputs)->catb; [4096,8192) cast(r)->rb.
__global__ __launch_bounds__(256) void k_prep_x(
    const float* __restrict__ mem, const float* __restrict__ inp,
    const float* __restrict__ r,
    bf16* __restrict__ catb, bf16* __restrict__ rb)
{
    const int id = blockIdx.x;
    if (id < 4096) {
        const int e   = (id * 256 + threadIdx.x) * 4;
        const int row = e >> 10, dc = e & 1023;
        const int b   = row >> 11, k = row & 2047;
        const float* src = (k < 1024) ? mem + ((size_t)b * 1024 + k) * 1024 + dc
                                      : inp + ((size_t)b * 1024 + (k - 1024)) * 1024 + dc;
        float4 f = *(const float4*)src;
        bf16x4 o; o[0] = (bf16)f.x; o[1] = (bf16)f.y; o[2] = (bf16)f.z; o[3] = (bf16)f.w;
        *(bf16x4*)&catb[e] = o;
    } else {
        const int e = ((id - 4096) * 256 + threadIdx.x) * 4;
        float4 f = *(const float4*)(r + e);
        bf16x4 o; o[0] = (bf16)f.x; o[1] = (bf16)f.y; o[2] = (bf16)f.z; o[3] = (bf16)f.w;
        *(bf16x4*)&rb[e] = o;
    }
}

// ------------------------------------------------- fused QKV + R GEMM
__global__ __launch_bounds__(256) void k_gemm_qkvr(
    const bf16* __restrict__ catb, const bf16* __restrict__ Wqkvt,
    const float* __restrict__ b_qkv, const float* __restrict__ u, const float* __restrict__ v,
    const bf16* __restrict__ rb_, const bf16* __restrict__ Wrt,
    const float* __restrict__ b_r,
    bf16* __restrict__ hq_u, bf16* __restrict__ hq_v,
    bf16* __restrict__ hk, bf16* __restrict__ hvT, bf16* __restrict__ hr)
{
    __shared__ bf16 lds[2 * 128 * 32];
    f32x4 acc[4][4];
    const int m0 = blockIdx.x * 128;
    const int lane = threadIdx.x & 63, wave = threadIdx.x >> 6;
    const int wr = (wave >> 1) * 64, wc = (wave & 1) * 64;
    const int lr = lane & 15, q4 = lane >> 4;

    if (blockIdx.y < 24) {
        const int n0 = blockIdx.y * 128;
        gemm128_core(catb, Wqkvt, 1024, m0, n0, lds, lds + 128 * 32, acc);
#pragma unroll
        for (int rb = 0; rb < 4; ++rb) {
#pragma unroll
            for (int cb = 0; cb < 4; ++cb) {
                const int col  = n0 + wc + cb * 16 + lr;
                const int part = col >> 10;
                const int hd   = col & 1023;
                const int h    = hd >> 6, d = hd & 63;
                const float bcol = b_qkv[col];
#pragma unroll
                for (int r = 0; r < 4; ++r) {
                    const int row = m0 + wr + rb * 16 + q4 * 4 + r;
                    const int b   = row >> 11, k = row & 2047;
                    const float val = acc[rb][cb][r] + bcol;
                    if (part == 0) {
                        if (k >= 1024) {
                            const size_t o = (((size_t)(b * 16 + h)) * 1024 + (k - 1024)) * 64 + d;
                            hq_u[o] = (bf16)(val + u[hd]);
                            hq_v[o] = (bf16)(val + v[hd]);
                        }
                    } else if (part == 1) {
                        hvT[(((size_t)(b * 16 + h)) * 64 + d) * 2048 + k] = (bf16)val;
                    } else {
                        hk[(((size_t)(b * 16 + h)) * 2048 + k) * 64 + d] = (bf16)val;
                    }
                }
            }
        }
    } else {
        const int n0 = (blockIdx.y - 24) * 128;
        gemm128_core(rb_, Wrt, 1024, m0, n0, lds, lds + 128 * 32, acc);
#pragma unroll
        for (int rb = 0; rb < 4; ++rb) {
#pragma unroll
            for (int cb = 0; cb < 4; ++cb) {
                const int col = n0 + wc + cb * 16 + lr;
                const int h = col >> 6, d = col & 63;
                const float bcol = b_r[col];
#pragma unroll
                for (int r = 0; r < 4; ++r) {
                    const int row = m0 + wr + rb * 16 + q4 * 4 + r;
                    const int b = row >> 11, k = row & 2047;
                    hr[(((size_t)(b * 16 + h)) * 2048 + k) * 64 + d] = (bf16)(acc[rb][cb][r] + bcol);
                }
            }
        }
    }
}

// ---------------------------------------------------------------- out GEMM
__global__ __launch_bounds__(256) void k_gemm_out(
    const bf16* __restrict__ attn, const bf16* __restrict__ Wt,
    const float* __restrict__ bias, float* __restrict__ out)
{
    __shared__ bf16 lds[2 * 128 * 32];
    f32x4 acc[4][4];
    const int m0 = blockIdx.x * 128, n0 = blockIdx.y * 128;
    gemm128_core(attn, Wt, 1024, m0, n0, lds, lds + 128 * 32, acc);

    const int lane = threadIdx.x & 63, wave = threadIdx.x >> 6;
    const int wr = (wave >> 1) * 64, wc = (wave & 1) * 64;
    const int lr = lane & 15, q4 = lane >> 4;
#pragma unroll
    for (int rb = 0; rb < 4; ++rb) {
#pragma unroll
        for (int cb = 0; cb < 4; ++cb) {
            const int col = n0 + wc + cb * 16 + lr;
            const float bcol = bias[col];
#pragma unroll
            for (int r = 0; r < 4; ++r) {
                const int row = m0 + wr + rb * 16 + q4 * 4 + r;
                out[(size_t)row * 1024 + col] = acc[rb][cb][r] + bcol;
            }
        }
    }
}

// -------------------------------------- fused attention (R13 base + BDT)
// One workgroup per (bh, 64-q tile). K/V double-buffered LDS; R rolling
// 3-slot window; ONE barrier per tile. BD tile now stored TRANSPOSED
// (BDT[col][row], stride 20 -> b64-aligned, bank-spread): the 4 per-lane
// row values pack into one ds_write_b64 (was 4 scalar b16 writes).
// Shifted read: bdv = BDT[cb*16+lr+15-tq][tq]. Ps view (stride 76) overlaps
// the slab; all BDT reads complete (into regs) before Ps writes, and DS ops
// within a wave are ordered => safe (same trick as R10-R13).
// LDS: Ks 18432 + Vt 18432 + Rs 27648 + U 4*3200 = 77312 B => 2 blocks/CU.
__global__ __launch_bounds__(256) void k_attn(
    const bf16* __restrict__ hq_u, const bf16* __restrict__ hq_v,
    const bf16* __restrict__ hk, const bf16* __restrict__ hvT,
    const bf16* __restrict__ hr, bf16* __restrict__ attn)
{
    __shared__ bf16 Ks[2][64][72];     // K tile [k][d], double-buffered
    __shared__ bf16 Vt[2][64][72];     // V tile [d][k], double-buffered
    __shared__ bf16 Rs[192 * 72];      // R rolling window: 3 slots x 64 rows
    __shared__ bf16 U[4][1600];        // per-wave: BDT [80][20] / Ps [16][76]

    const int bh = blockIdx.y;
    // complement remap: co-resident block pairs sum to uniform work.
    const int qt = (bh & 16) ? (15 - (int)blockIdx.x) : (int)blockIdx.x;
    const int q0 = qt * 64;
    const int tid = threadIdx.x, lane = tid & 63, wave = tid >> 6;
    const int lr = lane & 15, q4 = lane >> 4;
    bf16* Uw = &U[wave][0];

    const int nt  = 17 + qt;                  // K-tiles for this q-tile
    const int m0c = 15 - qt;                  // base R-chunk index at t=0
    const size_t kvbase = (size_t)bh * 2048 * 64;

    // fixed per-thread staging coordinates (64 rows x 64 cols per tile/chunk)
    const int ci0  = tid,        r0_ = ci0 >> 3,  c0_ = (ci0 & 7) * 8;
    const int ci1  = 256 + tid,  r1_ = ci1 >> 3,  c1_ = (ci1 & 7) * 8;

    // prefetch registers
    bf16x8 kv0, kv1, vv0, vv1, rv0, rv1;
    auto load_kv = [&](int t) {
        const int k0 = t * 64;
        kv0 = *(const bf16x8*)&hk [kvbase + (size_t)(k0 + r0_) * 64 + c0_];
        kv1 = *(const bf16x8*)&hk [kvbase + (size_t)(k0 + r1_) * 64 + c1_];
        vv0 = *(const bf16x8*)&hvT[kvbase + (size_t)r0_ * 2048 + k0 + c0_];
        vv1 = *(const bf16x8*)&hvT[kvbase + (size_t)r1_ * 2048 + k0 + c1_];
    };
    auto load_r = [&](int c) {               // R chunk c: global rows [64c, 64c+64)
        if (c * 64 < 2048) {
            rv0 = *(const bf16x8*)&hr[kvbase + (size_t)(c * 64 + r0_) * 64 + c0_];
            rv1 = *(const bf16x8*)&hr[kvbase + (size_t)(c * 64 + r1_) * 64 + c1_];
        } else {
#pragma unroll
            for (int z = 0; z < 8; ++z) { rv0[z] = (bf16)0.f; rv1[z] = (bf16)0.f; }
        }
    };
    auto write_kv = [&](int buf) {
        *(bf16x8*)&Ks[buf][r0_][c0_] = kv0;
        *(bf16x8*)&Ks[buf][r1_][c1_] = kv1;
        *(bf16x8*)&Vt[buf][r0_][c0_] = vv0;
        *(bf16x8*)&Vt[buf][r1_][c1_] = vv1;
    };
    auto write_r = [&](int slot) {
        *(bf16x8*)&Rs[(slot * 64 + r0_) * 72 + c0_] = rv0;
        *(bf16x8*)&Rs[(slot * 64 + r1_) * 72 + c1_] = rv1;
    };

    // Q fragments (A-operand layout: m = lane&15, k = (lane>>4)*8 + j)
    const size_t qrow = ((size_t)bh * 1024 + q0 + wave * 16 + lr) * 64;
    const bf16x8 qu0 = *(const bf16x8*)&hq_u[qrow + q4 * 8];
    const bf16x8 qu1 = *(const bf16x8*)&hq_u[qrow + 32 + q4 * 8];
    const bf16x8 qv0 = *(const bf16x8*)&hq_v[qrow + q4 * 8];
    const bf16x8 qv1 = *(const bf16x8*)&hq_v[qrow + 32 + q4 * 8];

    f32x4 Oacc[4];
#pragma unroll
    for (int i = 0; i < 4; ++i) { Oacc[i][0] = 0.f; Oacc[i][1] = 0.f; Oacc[i][2] = 0.f; Oacc[i][3] = 0.f; }
    float lp[4] = {0.f, 0.f, 0.f, 0.f};

    // prologue: stage K/V tile 0 + R chunks m0c, m0c+1
    load_kv(0);  write_kv(0);
    load_r(m0c);     write_r(m0c % 3);
    load_r(m0c + 1); write_r((m0c + 1) % 3);
    __syncthreads();

    for (int t = 0; t < nt; ++t) {
        const int k0  = t * 64;
        const int mt  = m0c + t;
        const int s0  = mt % 3;
        const int s1  = (s0 + 1 == 3) ? 0 : s0 + 1;
        const int s2  = (s1 + 1 == 3) ? 0 : s1 + 1;
        const int buf = t & 1;
        const bool more = (t + 1 < nt);
        // issue next tile's global loads NOW (overlap with compute below)
        if (more) { load_kv(t + 1); load_r(mt + 2); }

        __builtin_amdgcn_s_setprio(1);
        // ---- AC = (hq+u) @ K^T
        f32x4 S[4];
#pragma unroll
        for (int cb = 0; cb < 4; ++cb) {
            const bf16x8 kf0 = *(const bf16x8*)&Ks[buf][cb * 16 + lr][q4 * 8];
            const bf16x8 kf1 = *(const bf16x8*)&Ks[buf][cb * 16 + lr][32 + q4 * 8];
            f32x4 z; z[0] = 0.f; z[1] = 0.f; z[2] = 0.f; z[3] = 0.f;
            z = __builtin_amdgcn_mfma_f32_16x16x32_bf16(qu0, kf0, z, 0, 0, 0);
            S[cb] = __builtin_amdgcn_mfma_f32_16x16x32_bf16(qu1, kf1, z, 0, 0, 0);
        }
        // ---- BD band -> TRANSPOSED LDS view BDT[col][row], stride 20.
        //      One b64 write per (jbi) instead of 4 scalar b16 writes.
#pragma unroll
        for (int jbi = 0; jbi < 5; ++jbi) {
            const int jb   = jbi + 3 - wave;              // 0..7
            const int rrow = ((jb & 4) ? s1 : s0) * 64 + (jb & 3) * 16 + lr;
            const bf16x8 rf0 = *(const bf16x8*)&Rs[rrow * 72 + q4 * 8];
            const bf16x8 rf1 = *(const bf16x8*)&Rs[rrow * 72 + 32 + q4 * 8];
            f32x4 z; z[0] = 0.f; z[1] = 0.f; z[2] = 0.f; z[3] = 0.f;
            z = __builtin_amdgcn_mfma_f32_16x16x32_bf16(qv0, rf0, z, 0, 0, 0);
            z = __builtin_amdgcn_mfma_f32_16x16x32_bf16(qv1, rf1, z, 0, 0, 0);
            bf16x4 pk;
            pk[0] = (bf16)z[0]; pk[1] = (bf16)z[1]; pk[2] = (bf16)z[2]; pk[3] = (bf16)z[3];
            *(bf16x4*)&Uw[(jbi * 16 + lr) * 20 + q4 * 4] = pk;
        }

        // ---- read ALL shifted BD values into registers (before Ps writes)
        float bdv[4][4];
#pragma unroll
        for (int cb = 0; cb < 4; ++cb)
#pragma unroll
            for (int r = 0; r < 4; ++r) {
                const int tq = q4 * 4 + r;
                bdv[cb][r] = (float)Uw[(cb * 16 + lr + 15 - tq) * 20 + tq];
            }

        // ---- scores: mask, exp (no max), accumulate l, Ps write (stride 76)
#pragma unroll
        for (int cb = 0; cb < 4; ++cb) {
            const int k = k0 + cb * 16 + lr;
#pragma unroll
            for (int r = 0; r < 4; ++r) {
                const int q = q0 + wave * 16 + q4 * 4 + r;
                const float s = (S[cb][r] + bdv[cb][r]) * 0.125f;
                const float p = (k <= 1024 + q) ? __expf(s) : 0.f;
                lp[r] += p;
                Uw[(q4 * 4 + r) * 76 + cb * 16 + lr] = (bf16)p;   // Ps view
            }
        }

        // ---- PV: P (A-layout via Ps view) @ V
        const bf16x8 pf0 = *(const bf16x8*)&Uw[lr * 76 + q4 * 8];
        const bf16x8 pf1 = *(const bf16x8*)&Uw[lr * 76 + 32 + q4 * 8];
#pragma unroll
        for (int db = 0; db < 4; ++db) {
            const bf16x8 vf0 = *(const bf16x8*)&Vt[buf][db * 16 + lr][q4 * 8];
            const bf16x8 vf1 = *(const bf16x8*)&Vt[buf][db * 16 + lr][32 + q4 * 8];
            Oacc[db] = __builtin_amdgcn_mfma_f32_16x16x32_bf16(pf0, vf0, Oacc[db], 0, 0, 0);
            Oacc[db] = __builtin_amdgcn_mfma_f32_16x16x32_bf16(pf1, vf1, Oacc[db], 0, 0, 0);
        }
        __builtin_amdgcn_s_setprio(0);

        if (more) {
            // stage tile t+1 into the OTHER buffer / third R slot: disjoint
            // from everything read this iteration => no pre-write barrier.
            write_kv(buf ^ 1);
            write_r(s2);
            __syncthreads();           // make staged tile visible to all waves
        }
    }

    // ---- 16-lane row-sum of l, normalize, write
#pragma unroll
    for (int off = 1; off < 16; off <<= 1)
#pragma unroll
        for (int r = 0; r < 4; ++r) lp[r] += __shfl_xor(lp[r], off, 64);

    const int b = bh >> 4, h = bh & 15;
#pragma unroll
    for (int r = 0; r < 4; ++r) {
        const float rl = 1.f / lp[r];
        const int q = q0 + wave * 16 + q4 * 4 + r;
#pragma unroll
        for (int db = 0; db < 4; ++db) {
            const int d = db * 16 + lr;
            attn[(((size_t)b * 1024 + q) * 16 + h) * 64 + d] = (bf16)(Oacc[db][r] * rl);
        }
    }
}

// ------------------------------------------------------------------ launch
extern "C" void kernel_launch(void* const* d_in, const int* in_sizes, int n_in,
                              void* d_out, int out_size, void* d_ws, size_t ws_size,
                              hipStream_t stream)
{
    const float* inputs = (const float*)d_in[0];
    const float* mem    = (const float*)d_in[1];
    const float* r      = (const float*)d_in[2];
    const float* W_qkv  = (const float*)d_in[3];
    const float* b_qkv  = (const float*)d_in[4];
    const float* W_r    = (const float*)d_in[5];
    const float* b_r    = (const float*)d_in[6];
    const float* W_o    = (const float*)d_in[7];
    const float* b_o    = (const float*)d_in[8];
    const float* u      = (const float*)d_in[9];
    const float* v      = (const float*)d_in[10];
    float* out = (float*)d_out;

    char* ws = (char*)d_ws;
    size_t off = 0;
    auto alloc = [&](size_t bytes) -> void* {
        void* p = ws + off;
        off += (bytes + 255) & ~(size_t)255;
        return p;
    };
    bf16* hq_u  = (bf16*)alloc(2ull * 16 * 1024 * 64 * 2);
    bf16* hq_v  = (bf16*)alloc(2ull * 16 * 1024 * 64 * 2);
    bf16* hk    = (bf16*)alloc(2ull * 16 * 2048 * 64 * 2);
    bf16* hvT   = (bf16*)alloc(2ull * 16 * 2048 * 64 * 2);
    bf16* hr    = (bf16*)alloc(2ull * 16 * 2048 * 64 * 2);
    bf16* attnb = (bf16*)alloc(2ull * 1024 * 1024 * 2);
    bf16* Wot   = (bf16*)alloc(1024ull * 1024 * 2);
    bf16* catb  = (bf16*)alloc(4096ull * 1024 * 2);
    bf16* rb    = (bf16*)alloc(4096ull * 1024 * 2);
    bf16* Wqkvt = (bf16*)alloc(3072ull * 1024 * 2);
    bf16* Wrt   = (bf16*)alloc(1024ull * 1024 * 2);

    k_prep_w<<<5120, 256, 0, stream>>>(W_qkv, W_r, W_o, Wqkvt, Wrt, Wot);
    k_prep_x<<<8192, 256, 0, stream>>>(mem, inputs, r, catb, rb);

    k_gemm_qkvr<<<dim3(32, 32), 256, 0, stream>>>(catb, Wqkvt, b_qkv, u, v,
                                                  rb, Wrt, b_r,
                                                  hq_u, hq_v, hk, hvT, hr);
    k_attn<<<dim3(16, 32), 256, 0, stream>>>(hq_u, hq_v, hk, hvT, hr, attnb);
    k_gemm_out<<<dim3(16, 8), 256, 0, stream>>>(attnb, Wot, b_o, out);
}

// Round 8
// 249.911 us; speedup vs baseline: 1.3574x; 1.0471x over previous
//
#include <hip/hip_runtime.h>
#include <hip/hip_bf16.h>
#include <stdint.h>

// Transformer-XL relative MHA on MI355X (gfx950), bf16 MFMA pipeline.
// B=2, Q=1024, M=1024, D=1024, H=16, DH=64, K=2048.
// Evidence log:
//  - R5 failure isolated to bpermute block-selection (banned).
//  - R9/R10: K-split regressed; occupancy pinned ~2 blocks/CU (grid-limited).
//  - R12: qt complement-remap; setprio; dead-tail skip. 305->287.
//  - R13: rolling R window + single barrier + fused qkvr GEMM. 287->272.
//  - R14 REFUTED (153 us): register-direct K/V/R = per-lane gathers + loads
//    sunk to uses. LDS staging is a gather->coalesce converter. Reverted.
//  - R15: BDT b64 writes + merged preps. 272->261.7; k_attn now <92 us and
//    k_gemm_qkvr (92 us, MfmaUtil 14.3%, 374 TF ~= m102 shape curve) is top.
//  - R16 (this): (a) stop computing discarded q-rows: QKV split into KV-part
//    (all 4096 rows x cols 1024..3072) + Q-part (2048 input rows only x cols
//    0..1024): -4.3 GFLOP, -128 blocks. Grid (32,28): y<16 KV, y in [16,20)
//    Q (linear remap), y in [20,28) R. (b) k_gemm_out 64x128 tiles
//    (gemm64_core): 128 -> 256 blocks, full-GPU occupancy.

typedef __bf16 bf16;
typedef __bf16 bf16x2 __attribute__((ext_vector_type(2)));
typedef __bf16 bf16x4 __attribute__((ext_vector_type(4)));
typedef __bf16 bf16x8 __attribute__((ext_vector_type(8)));
typedef float  f32x4  __attribute__((ext_vector_type(4)));

// ---------------------------------------------------------------- async copy
__device__ __forceinline__ void async_copy16(void* lds, const void* g) {
    auto gp = (const __attribute__((address_space(1))) void*)(uintptr_t)g;
    auto lp = (__attribute__((address_space(3))) void*)(uint32_t)(uintptr_t)lds;
    __builtin_amdgcn_global_load_lds(gp, lp, 16, 0, 0);
}

// ------------------------------------------------------- 128x128 GEMM core
__device__ __forceinline__ void gemm128_core(
    const bf16* __restrict__ A, const bf16* __restrict__ Bt, const int Kd,
    const int m0, const int n0, bf16* As, bf16* Bs, f32x4 acc[4][4])
{
    const int tid  = threadIdx.x;
    const int lane = tid & 63;
    const int wave = tid >> 6;
    const int wr   = (wave >> 1) * 64;
    const int wc   = (wave & 1) * 64;
    const int lr   = lane & 15;
    const int q4   = lane >> 4;

#pragma unroll
    for (int i = 0; i < 4; ++i)
#pragma unroll
        for (int j = 0; j < 4; ++j) {
            acc[i][j][0] = 0.f; acc[i][j][1] = 0.f; acc[i][j][2] = 0.f; acc[i][j][3] = 0.f;
        }

    for (int k0 = 0; k0 < Kd; k0 += 32) {
#pragma unroll
        for (int it = 0; it < 2; ++it) {
            const int cb0   = (it * 4 + wave) * 64;   // wave-uniform chunk base
            const int chunk = cb0 + lane;
            const int row   = chunk >> 2;
            const int cg    = (chunk & 3) * 8;
            async_copy16(As + cb0 * 8, A  + (size_t)(m0 + row) * Kd + k0 + cg);
            async_copy16(Bs + cb0 * 8, Bt + (size_t)(n0 + row) * Kd + k0 + cg);
        }
        __syncthreads();
        bf16x8 af[4], bfr[4];
#pragma unroll
        for (int rb = 0; rb < 4; ++rb)
            af[rb] = *(const bf16x8*)&As[(wr + rb * 16 + lr) * 32 + q4 * 8];
#pragma unroll
        for (int cb = 0; cb < 4; ++cb)
            bfr[cb] = *(const bf16x8*)&Bs[(wc + cb * 16 + lr) * 32 + q4 * 8];
#pragma unroll
        for (int rb = 0; rb < 4; ++rb)
#pragma unroll
            for (int cb = 0; cb < 4; ++cb)
                acc[rb][cb] = __builtin_amdgcn_mfma_f32_16x16x32_bf16(af[rb], bfr[cb], acc[rb][cb], 0, 0, 0);
        __syncthreads();
    }
}

// -------------------------------------------------------- 64x128 GEMM core
// C[64,128]: 4 waves as 2x2; each wave 32 rows x 64 cols; acc[2][4].
__device__ __forceinline__ void gemm64_core(
    const bf16* __restrict__ A, const bf16* __restrict__ Bt, const int Kd,
    const int m0, const int n0, bf16* As, bf16* Bs, f32x4 acc[2][4])
{
    const int tid  = threadIdx.x;
    const int lane = tid & 63;
    const int wave = tid >> 6;
    const int wr   = (wave >> 1) * 32;
    const int wc   = (wave & 1) * 64;
    const int lr   = lane & 15;
    const int q4   = lane >> 4;

#pragma unroll
    for (int i = 0; i < 2; ++i)
#pragma unroll
        for (int j = 0; j < 4; ++j) {
            acc[i][j][0] = 0.f; acc[i][j][1] = 0.f; acc[i][j][2] = 0.f; acc[i][j][3] = 0.f;
        }

    for (int k0 = 0; k0 < Kd; k0 += 32) {
        {   // A tile 64x32: 256 chunks, one per thread
            const int chunk = tid;
            const int row   = chunk >> 2;
            const int cg    = (chunk & 3) * 8;
            async_copy16(As + (wave * 64) * 8, A + (size_t)(m0 + row) * Kd + k0 + cg);
        }
#pragma unroll
        for (int it = 0; it < 2; ++it) {   // B tile 128x32: 512 chunks
            const int cb0   = (it * 4 + wave) * 64;
            const int chunk = cb0 + lane;
            const int row   = chunk >> 2;
            const int cg    = (chunk & 3) * 8;
            async_copy16(Bs + cb0 * 8, Bt + (size_t)(n0 + row) * Kd + k0 + cg);
        }
        __syncthreads();
        bf16x8 af[2], bfr[4];
#pragma unroll
        for (int rb = 0; rb < 2; ++rb)
            af[rb] = *(const bf16x8*)&As[(wr + rb * 16 + lr) * 32 + q4 * 8];
#pragma unroll
        for (int cb = 0; cb < 4; ++cb)
            bfr[cb] = *(const bf16x8*)&Bs[(wc + cb * 16 + lr) * 32 + q4 * 8];
#pragma unroll
        for (int rb = 0; rb < 2; ++rb)
#pragma unroll
            for (int cb = 0; cb < 4; ++cb)
                acc[rb][cb] = __builtin_amdgcn_mfma_f32_16x16x32_bf16(af[rb], bfr[cb], acc[rb][cb], 0, 0, 0);
        __syncthreads();
    }
}

// -------------------------------------------------- merged prep: weights
__global__ __launch_bounds__(256) void k_prep_w(
    const float* __restrict__ Wqkv, const float* __restrict__ Wr,
    const float* __restrict__ Wo,
    bf16* __restrict__ Wqkvt, bf16* __restrict__ Wrt, bf16* __restrict__ Wot)
{
    __shared__ float t[32][33];
    int id = blockIdx.x;
    const float* in; bf16* out; int C, bx, by;
    if (id < 3072)      { in = Wqkv; out = Wqkvt; C = 3072; bx = id % 96; by = id / 96; }
    else if (id < 4096) { id -= 3072; in = Wr; out = Wrt; C = 1024; bx = id & 31; by = id >> 5; }
    else                { id -= 4096; in = Wo; out = Wot; C = 1024; bx = id & 31; by = id >> 5; }
    const int R = 1024;
    const int c0 = bx * 32, r0 = by * 32;
    const int lc = threadIdx.x & 31, lrow = threadIdx.x >> 5;
#pragma unroll
    for (int p = 0; p < 4; ++p)
        t[lrow + p * 8][lc] = in[(size_t)(r0 + lrow + p * 8) * C + c0 + lc];
    __syncthreads();
#pragma unroll
    for (int p = 0; p < 4; ++p)
        out[(size_t)(c0 + lrow + p * 8) * R + r0 + lc] = (bf16)t[lc][lrow + p * 8];
}

// -------------------------------------------------- merged prep: activations
__global__ __launch_bounds__(256) void k_prep_x(
    const float* __restrict__ mem, const float* __restrict__ inp,
    const float* __restrict__ r,
    bf16* __restrict__ catb, bf16* __restrict__ rb)
{
    const int id = blockIdx.x;
    if (id < 4096) {
        const int e   = (id * 256 + threadIdx.x) * 4;
        const int row = e >> 10, dc = e & 1023;
        const int b   = row >> 11, k = row & 2047;
        const float* src = (k < 1024) ? mem + ((size_t)b * 1024 + k) * 1024 + dc
                                      : inp + ((size_t)b * 1024 + (k - 1024)) * 1024 + dc;
        float4 f = *(const float4*)src;
        bf16x4 o; o[0] = (bf16)f.x; o[1] = (bf16)f.y; o[2] = (bf16)f.z; o[3] = (bf16)f.w;
        *(bf16x4*)&catb[e] = o;
    } else {
        const int e = ((id - 4096) * 256 + threadIdx.x) * 4;
        float4 f = *(const float4*)(r + e);
        bf16x4 o; o[0] = (bf16)f.x; o[1] = (bf16)f.y; o[2] = (bf16)f.z; o[3] = (bf16)f.w;
        *(bf16x4*)&rb[e] = o;
    }
}

// ------------------------------------------------- fused KV + Q + R GEMM
// grid (32, 28):
//  y in [0,16):  KV-part: all 4096 rows x cols n0=1024+y*128 (v,k outputs).
//  y in [16,20): Q-part: linear=(y-16)*32+x in [0,128); n0=(linear&7)*128;
//                mi=linear>>3 in [0,16): m0 = (mi>>3)*2048 + 1024 + (mi&7)*128
//                (input rows only; q output with +u/+v).
//  y in [20,28): R GEMM: n0=(y-20)*128, all rows.
__global__ __launch_bounds__(256) void k_gemm_qkvr(
    const bf16* __restrict__ catb, const bf16* __restrict__ Wqkvt,
    const float* __restrict__ b_qkv, const float* __restrict__ u, const float* __restrict__ v,
    const bf16* __restrict__ rb_, const bf16* __restrict__ Wrt,
    const float* __restrict__ b_r,
    bf16* __restrict__ hq_u, bf16* __restrict__ hq_v,
    bf16* __restrict__ hk, bf16* __restrict__ hvT, bf16* __restrict__ hr)
{
    __shared__ bf16 lds[2 * 128 * 32];
    f32x4 acc[4][4];
    const int lane = threadIdx.x & 63, wave = threadIdx.x >> 6;
    const int wr = (wave >> 1) * 64, wc = (wave & 1) * 64;
    const int lr = lane & 15, q4 = lane >> 4;
    const int y = blockIdx.y;

    if (y < 16) {                       // ---- KV part
        const int m0 = blockIdx.x * 128;
        const int n0 = 1024 + y * 128;
        gemm128_core(catb, Wqkvt, 1024, m0, n0, lds, lds + 128 * 32, acc);
#pragma unroll
        for (int rb = 0; rb < 4; ++rb) {
#pragma unroll
            for (int cb = 0; cb < 4; ++cb) {
                const int col  = n0 + wc + cb * 16 + lr;
                const int part = col >> 10;             // 1 or 2
                const int hd   = col & 1023;
                const int h    = hd >> 6, d = hd & 63;
                const float bcol = b_qkv[col];
#pragma unroll
                for (int r = 0; r < 4; ++r) {
                    const int row = m0 + wr + rb * 16 + q4 * 4 + r;
                    const int b   = row >> 11, k = row & 2047;
                    const float val = acc[rb][cb][r] + bcol;
                    if (part == 1) {
                        hvT[(((size_t)(b * 16 + h)) * 64 + d) * 2048 + k] = (bf16)val;
                    } else {
                        hk[(((size_t)(b * 16 + h)) * 2048 + k) * 64 + d] = (bf16)val;
                    }
                }
            }
        }
    } else if (y < 20) {                // ---- Q part (input rows only)
        const int linear = (y - 16) * 32 + blockIdx.x;   // [0,128)
        const int n0 = (linear & 7) * 128;
        const int mi = linear >> 3;                       // [0,16)
        const int m0 = (mi >> 3) * 2048 + 1024 + (mi & 7) * 128;
        gemm128_core(catb, Wqkvt, 1024, m0, n0, lds, lds + 128 * 32, acc);
#pragma unroll
        for (int rb = 0; rb < 4; ++rb) {
#pragma unroll
            for (int cb = 0; cb < 4; ++cb) {
                const int col = n0 + wc + cb * 16 + lr;   // [0,1024)
                const int h = col >> 6, d = col & 63;
                const float bcol = b_qkv[col];
                const float uc = u[col], vc = v[col];
#pragma unroll
                for (int r = 0; r < 4; ++r) {
                    const int row = m0 + wr + rb * 16 + q4 * 4 + r;
                    const int b   = row >> 11, k = row & 2047;   // k in [1024,2048)
                    const float val = acc[rb][cb][r] + bcol;
                    const size_t o = (((size_t)(b * 16 + h)) * 1024 + (k - 1024)) * 64 + d;
                    hq_u[o] = (bf16)(val + uc);
                    hq_v[o] = (bf16)(val + vc);
                }
            }
        }
    } else {                            // ---- R GEMM
        const int m0 = blockIdx.x * 128;
        const int n0 = (y - 20) * 128;
        gemm128_core(rb_, Wrt, 1024, m0, n0, lds, lds + 128 * 32, acc);
#pragma unroll
        for (int rb = 0; rb < 4; ++rb) {
#pragma unroll
            for (int cb = 0; cb < 4; ++cb) {
                const int col = n0 + wc + cb * 16 + lr;
                const int h = col >> 6, d = col & 63;
                const float bcol = b_r[col];
#pragma unroll
                for (int r = 0; r < 4; ++r) {
                    const int row = m0 + wr + rb * 16 + q4 * 4 + r;
                    const int b = row >> 11, k = row & 2047;
                    hr[(((size_t)(b * 16 + h)) * 2048 + k) * 64 + d] = (bf16)(acc[rb][cb][r] + bcol);
                }
            }
        }
    }
}

// -------------------------------------------------- out GEMM (64x128 tiles)
__global__ __launch_bounds__(256) void k_gemm_out(
    const bf16* __restrict__ attn, const bf16* __restrict__ Wt,
    const float* __restrict__ bias, float* __restrict__ out)
{
    __shared__ bf16 lds[64 * 32 + 128 * 32];
    f32x4 acc[2][4];
    const int m0 = blockIdx.x * 64, n0 = blockIdx.y * 128;
    gemm64_core(attn, Wt, 1024, m0, n0, lds, lds + 64 * 32, acc);

    const int lane = threadIdx.x & 63, wave = threadIdx.x >> 6;
    const int wr = (wave >> 1) * 32, wc = (wave & 1) * 64;
    const int lr = lane & 15, q4 = lane >> 4;
#pragma unroll
    for (int rb = 0; rb < 2; ++rb) {
#pragma unroll
        for (int cb = 0; cb < 4; ++cb) {
            const int col = n0 + wc + cb * 16 + lr;
            const float bcol = bias[col];
#pragma unroll
            for (int r = 0; r < 4; ++r) {
                const int row = m0 + wr + rb * 16 + q4 * 4 + r;
                out[(size_t)row * 1024 + col] = acc[rb][cb][r] + bcol;
            }
        }
    }
}

// -------------------------------------- fused attention (R13 base + BDT)
__global__ __launch_bounds__(256) void k_attn(
    const bf16* __restrict__ hq_u, const bf16* __restrict__ hq_v,
    const bf16* __restrict__ hk, const bf16* __restrict__ hvT,
    const bf16* __restrict__ hr, bf16* __restrict__ attn)
{
    __shared__ bf16 Ks[2][64][72];     // K tile [k][d], double-buffered
    __shared__ bf16 Vt[2][64][72];     // V tile [d][k], double-buffered
    __shared__ bf16 Rs[192 * 72];      // R rolling window: 3 slots x 64 rows
    __shared__ bf16 U[4][1600];        // per-wave: BDT [80][20] / Ps [16][76]

    const int bh = blockIdx.y;
    const int qt = (bh & 16) ? (15 - (int)blockIdx.x) : (int)blockIdx.x;
    const int q0 = qt * 64;
    const int tid = threadIdx.x, lane = tid & 63, wave = tid >> 6;
    const int lr = lane & 15, q4 = lane >> 4;
    bf16* Uw = &U[wave][0];

    const int nt  = 17 + qt;
    const int m0c = 15 - qt;
    const size_t kvbase = (size_t)bh * 2048 * 64;

    const int ci0  = tid,        r0_ = ci0 >> 3,  c0_ = (ci0 & 7) * 8;
    const int ci1  = 256 + tid,  r1_ = ci1 >> 3,  c1_ = (ci1 & 7) * 8;

    bf16x8 kv0, kv1, vv0, vv1, rv0, rv1;
    auto load_kv = [&](int t) {
        const int k0 = t * 64;
        kv0 = *(const bf16x8*)&hk [kvbase + (size_t)(k0 + r0_) * 64 + c0_];
        kv1 = *(const bf16x8*)&hk [kvbase + (size_t)(k0 + r1_) * 64 + c1_];
        vv0 = *(const bf16x8*)&hvT[kvbase + (size_t)r0_ * 2048 + k0 + c0_];
        vv1 = *(const bf16x8*)&hvT[kvbase + (size_t)r1_ * 2048 + k0 + c1_];
    };
    auto load_r = [&](int c) {
        if (c * 64 < 2048) {
            rv0 = *(const bf16x8*)&hr[kvbase + (size_t)(c * 64 + r0_) * 64 + c0_];
            rv1 = *(const bf16x8*)&hr[kvbase + (size_t)(c * 64 + r1_) * 64 + c1_];
        } else {
#pragma unroll
            for (int z = 0; z < 8; ++z) { rv0[z] = (bf16)0.f; rv1[z] = (bf16)0.f; }
        }
    };
    auto write_kv = [&](int buf) {
        *(bf16x8*)&Ks[buf][r0_][c0_] = kv0;
        *(bf16x8*)&Ks[buf][r1_][c1_] = kv1;
        *(bf16x8*)&Vt[buf][r0_][c0_] = vv0;
        *(bf16x8*)&Vt[buf][r1_][c1_] = vv1;
    };
    auto write_r = [&](int slot) {
        *(bf16x8*)&Rs[(slot * 64 + r0_) * 72 + c0_] = rv0;
        *(bf16x8*)&Rs[(slot * 64 + r1_) * 72 + c1_] = rv1;
    };

    const size_t qrow = ((size_t)bh * 1024 + q0 + wave * 16 + lr) * 64;
    const bf16x8 qu0 = *(const bf16x8*)&hq_u[qrow + q4 * 8];
    const bf16x8 qu1 = *(const bf16x8*)&hq_u[qrow + 32 + q4 * 8];
    const bf16x8 qv0 = *(const bf16x8*)&hq_v[qrow + q4 * 8];
    const bf16x8 qv1 = *(const bf16x8*)&hq_v[qrow + 32 + q4 * 8];

    f32x4 Oacc[4];
#pragma unroll
    for (int i = 0; i < 4; ++i) { Oacc[i][0] = 0.f; Oacc[i][1] = 0.f; Oacc[i][2] = 0.f; Oacc[i][3] = 0.f; }
    float lp[4] = {0.f, 0.f, 0.f, 0.f};

    load_kv(0);  write_kv(0);
    load_r(m0c);     write_r(m0c % 3);
    load_r(m0c + 1); write_r((m0c + 1) % 3);
    __syncthreads();

    for (int t = 0; t < nt; ++t) {
        const int k0  = t * 64;
        const int mt  = m0c + t;
        const int s0  = mt % 3;
        const int s1  = (s0 + 1 == 3) ? 0 : s0 + 1;
        const int s2  = (s1 + 1 == 3) ? 0 : s1 + 1;
        const int buf = t & 1;
        const bool more = (t + 1 < nt);
        if (more) { load_kv(t + 1); load_r(mt + 2); }

        __builtin_amdgcn_s_setprio(1);
        // ---- AC = (hq+u) @ K^T
        f32x4 S[4];
#pragma unroll
        for (int cb = 0; cb < 4; ++cb) {
            const bf16x8 kf0 = *(const bf16x8*)&Ks[buf][cb * 16 + lr][q4 * 8];
            const bf16x8 kf1 = *(const bf16x8*)&Ks[buf][cb * 16 + lr][32 + q4 * 8];
            f32x4 z; z[0] = 0.f; z[1] = 0.f; z[2] = 0.f; z[3] = 0.f;
            z = __builtin_amdgcn_mfma_f32_16x16x32_bf16(qu0, kf0, z, 0, 0, 0);
            S[cb] = __builtin_amdgcn_mfma_f32_16x16x32_bf16(qu1, kf1, z, 0, 0, 0);
        }
        // ---- BD band -> transposed BDT view (stride 20), b64 writes
#pragma unroll
        for (int jbi = 0; jbi < 5; ++jbi) {
            const int jb   = jbi + 3 - wave;
            const int rrow = ((jb & 4) ? s1 : s0) * 64 + (jb & 3) * 16 + lr;
            const bf16x8 rf0 = *(const bf16x8*)&Rs[rrow * 72 + q4 * 8];
            const bf16x8 rf1 = *(const bf16x8*)&Rs[rrow * 72 + 32 + q4 * 8];
            f32x4 z; z[0] = 0.f; z[1] = 0.f; z[2] = 0.f; z[3] = 0.f;
            z = __builtin_amdgcn_mfma_f32_16x16x32_bf16(qv0, rf0, z, 0, 0, 0);
            z = __builtin_amdgcn_mfma_f32_16x16x32_bf16(qv1, rf1, z, 0, 0, 0);
            bf16x4 pk;
            pk[0] = (bf16)z[0]; pk[1] = (bf16)z[1]; pk[2] = (bf16)z[2]; pk[3] = (bf16)z[3];
            *(bf16x4*)&Uw[(jbi * 16 + lr) * 20 + q4 * 4] = pk;
        }

        // ---- shifted BD reads into registers (before Ps writes)
        float bdv[4][4];
#pragma unroll
        for (int cb = 0; cb < 4; ++cb)
#pragma unroll
            for (int r = 0; r < 4; ++r) {
                const int tq = q4 * 4 + r;
                bdv[cb][r] = (float)Uw[(cb * 16 + lr + 15 - tq) * 20 + tq];
            }

        // ---- scores: mask, exp, accumulate l, Ps write (stride 76)
#pragma unroll
        for (int cb = 0; cb < 4; ++cb) {
            const int k = k0 + cb * 16 + lr;
#pragma unroll
            for (int r = 0; r < 4; ++r) {
                const int q = q0 + wave * 16 + q4 * 4 + r;
                const float s = (S[cb][r] + bdv[cb][r]) * 0.125f;
                const float p = (k <= 1024 + q) ? __expf(s) : 0.f;
                lp[r] += p;
                Uw[(q4 * 4 + r) * 76 + cb * 16 + lr] = (bf16)p;
            }
        }

        // ---- PV
        const bf16x8 pf0 = *(const bf16x8*)&Uw[lr * 76 + q4 * 8];
        const bf16x8 pf1 = *(const bf16x8*)&Uw[lr * 76 + 32 + q4 * 8];
#pragma unroll
        for (int db = 0; db < 4; ++db) {
            const bf16x8 vf0 = *(const bf16x8*)&Vt[buf][db * 16 + lr][q4 * 8];
            const bf16x8 vf1 = *(const bf16x8*)&Vt[buf][db * 16 + lr][32 + q4 * 8];
            Oacc[db] = __builtin_amdgcn_mfma_f32_16x16x32_bf16(pf0, vf0, Oacc[db], 0, 0, 0);
            Oacc[db] = __builtin_amdgcn_mfma_f32_16x16x32_bf16(pf1, vf1, Oacc[db], 0, 0, 0);
        }
        __builtin_amdgcn_s_setprio(0);

        if (more) {
            write_kv(buf ^ 1);
            write_r(s2);
            __syncthreads();
        }
    }

    // ---- 16-lane row-sum of l, normalize, write
#pragma unroll
    for (int off = 1; off < 16; off <<= 1)
#pragma unroll
        for (int r = 0; r < 4; ++r) lp[r] += __shfl_xor(lp[r], off, 64);

    const int b = bh >> 4, h = bh & 15;
#pragma unroll
    for (int r = 0; r < 4; ++r) {
        const float rl = 1.f / lp[r];
        const int q = q0 + wave * 16 + q4 * 4 + r;
#pragma unroll
        for (int db = 0; db < 4; ++db) {
            const int d = db * 16 + lr;
            attn[(((size_t)b * 1024 + q) * 16 + h) * 64 + d] = (bf16)(Oacc[db][r] * rl);
        }
    }
}

// ------------------------------------------------------------------ launch
extern "C" void kernel_launch(void* const* d_in, const int* in_sizes, int n_in,
                              void* d_out, int out_size, void* d_ws, size_t ws_size,
                              hipStream_t stream)
{
    const float* inputs = (const float*)d_in[0];
    const float* mem    = (const float*)d_in[1];
    const float* r      = (const float*)d_in[2];
    const float* W_qkv  = (const float*)d_in[3];
    const float* b_qkv  = (const float*)d_in[4];
    const float* W_r    = (const float*)d_in[5];
    const float* b_r    = (const float*)d_in[6];
    const float* W_o    = (const float*)d_in[7];
    const float* b_o    = (const float*)d_in[8];
    const float* u      = (const float*)d_in[9];
    const float* v      = (const float*)d_in[10];
    float* out = (float*)d_out;

    char* ws = (char*)d_ws;
    size_t off = 0;
    auto alloc = [&](size_t bytes) -> void* {
        void* p = ws + off;
        off += (bytes + 255) & ~(size_t)255;
        return p;
    };
    bf16* hq_u  = (bf16*)alloc(2ull * 16 * 1024 * 64 * 2);
    bf16* hq_v  = (bf16*)alloc(2ull * 16 * 1024 * 64 * 2);
    bf16* hk    = (bf16*)alloc(2ull * 16 * 2048 * 64 * 2);
    bf16* hvT   = (bf16*)alloc(2ull * 16 * 2048 * 64 * 2);
    bf16* hr    = (bf16*)alloc(2ull * 16 * 2048 * 64 * 2);
    bf16* attnb = (bf16*)alloc(2ull * 1024 * 1024 * 2);
    bf16* Wot   = (bf16*)alloc(1024ull * 1024 * 2);
    bf16* catb  = (bf16*)alloc(4096ull * 1024 * 2);
    bf16* rb    = (bf16*)alloc(4096ull * 1024 * 2);
    bf16* Wqkvt = (bf16*)alloc(3072ull * 1024 * 2);
    bf16* Wrt   = (bf16*)alloc(1024ull * 1024 * 2);

    k_prep_w<<<5120, 256, 0, stream>>>(W_qkv, W_r, W_o, Wqkvt, Wrt, Wot);
    k_prep_x<<<8192, 256, 0, stream>>>(mem, inputs, r, catb, rb);

    k_gemm_qkvr<<<dim3(32, 28), 256, 0, stream>>>(catb, Wqkvt, b_qkv, u, v,
                                                  rb, Wrt, b_r,
                                                  hq_u, hq_v, hk, hvT, hr);
    k_attn<<<dim3(16, 32), 256, 0, stream>>>(hq_u, hq_v, hk, hvT, hr, attnb);
    k_gemm_out<<<dim3(32, 8), 256, 0, stream>>>(attnb, Wot, b_o, out);
}

// Round 9
// 248.795 us; speedup vs baseline: 1.3635x; 1.0045x over previous
//
#include <hip/hip_runtime.h>
#include <hip/hip_bf16.h>
#include <stdint.h>

// Transformer-XL relative MHA on MI355X (gfx950), bf16 MFMA pipeline.
// B=2, Q=1024, M=1024, D=1024, H=16, DH=64, K=2048.
// Evidence log:
//  - R5 failure isolated to bpermute block-selection (banned).
//  - R9/R10: K-split regressed; occupancy pinned ~2 blocks/CU (grid-limited).
//  - R12: qt complement-remap; setprio; dead-tail skip. 305->287.
//  - R13: rolling R window + single barrier + fused qkvr GEMM. 287->272.
//  - R14 REFUTED (153 us): register-direct K/V/R = per-lane gathers + loads
//    sunk to uses. LDS staging is a gather->coalesce converter. Reverted.
//  - R15: BDT b64 writes + merged preps. 272->261.7.
//  - R16: QKV split (skip discarded q-rows, -4.3 GFLOP) + 64x128 out GEMM.
//    261.7->249.9. k_attn 76.4 top; qkvr <76. attn LDS model holds; all
//    structural attn fixes hit the 160KB/2-block occupancy wall -> attn kept.
//  - R17 (this): GEMM cores double-buffered+prefetched (T3-minimum): stage
//    K-step t+1 BEFORE computing t, ONE barrier per step (was: stage t,
//    barrier, compute t, barrier => exposed HBM latency every 32-K step).
//    Hazards: iter-t writes buf^1, reads buf; barrier orders both. Preps
//    merged into one launch (routing only). k_attn byte-identical to R16.

typedef __bf16 bf16;
typedef __bf16 bf16x2 __attribute__((ext_vector_type(2)));
typedef __bf16 bf16x4 __attribute__((ext_vector_type(4)));
typedef __bf16 bf16x8 __attribute__((ext_vector_type(8)));
typedef float  f32x4  __attribute__((ext_vector_type(4)));

// ---------------------------------------------------------------- async copy
__device__ __forceinline__ void async_copy16(void* lds, const void* g) {
    auto gp = (const __attribute__((address_space(1))) void*)(uintptr_t)g;
    auto lp = (__attribute__((address_space(3))) void*)(uint32_t)(uintptr_t)lds;
    __builtin_amdgcn_global_load_lds(gp, lp, 16, 0, 0);
}

// ------------------------- 128x128 GEMM core, double-buffered prefetch (R17)
// As/Bs each 2*128*32 elements. One __syncthreads per K-step: stage(t+1)
// issued first, latency hidden under ds_read+MFMA of step t, barrier drains.
__device__ __forceinline__ void gemm128_core(
    const bf16* __restrict__ A, const bf16* __restrict__ Bt, const int Kd,
    const int m0, const int n0, bf16* As, bf16* Bs, f32x4 acc[4][4])
{
    const int tid  = threadIdx.x;
    const int lane = tid & 63;
    const int wave = tid >> 6;
    const int wr   = (wave >> 1) * 64;
    const int wc   = (wave & 1) * 64;
    const int lr   = lane & 15;
    const int q4   = lane >> 4;

#pragma unroll
    for (int i = 0; i < 4; ++i)
#pragma unroll
        for (int j = 0; j < 4; ++j) {
            acc[i][j][0] = 0.f; acc[i][j][1] = 0.f; acc[i][j][2] = 0.f; acc[i][j][3] = 0.f;
        }

    auto stage = [&](int buf, int k0) {
#pragma unroll
        for (int it = 0; it < 2; ++it) {
            const int cb0   = (it * 4 + wave) * 64;   // wave-uniform chunk base
            const int chunk = cb0 + lane;
            const int row   = chunk >> 2;
            const int cg    = (chunk & 3) * 8;
            async_copy16(As + buf * 4096 + cb0 * 8, A  + (size_t)(m0 + row) * Kd + k0 + cg);
            async_copy16(Bs + buf * 4096 + cb0 * 8, Bt + (size_t)(n0 + row) * Kd + k0 + cg);
        }
    };

    const int NT = Kd >> 5;
    stage(0, 0);
    __syncthreads();                       // tile 0 staged

    for (int t = 0; t < NT; ++t) {
        const int buf = t & 1;
        if (t + 1 < NT) stage(buf ^ 1, (t + 1) * 32);   // prefetch next step

        const bf16* Ab = As + buf * 4096;
        const bf16* Bb = Bs + buf * 4096;
        bf16x8 af[4], bfr[4];
#pragma unroll
        for (int rb = 0; rb < 4; ++rb)
            af[rb] = *(const bf16x8*)&Ab[(wr + rb * 16 + lr) * 32 + q4 * 8];
#pragma unroll
        for (int cb = 0; cb < 4; ++cb)
            bfr[cb] = *(const bf16x8*)&Bb[(wc + cb * 16 + lr) * 32 + q4 * 8];
#pragma unroll
        for (int rb = 0; rb < 4; ++rb)
#pragma unroll
            for (int cb = 0; cb < 4; ++cb)
                acc[rb][cb] = __builtin_amdgcn_mfma_f32_16x16x32_bf16(af[rb], bfr[cb], acc[rb][cb], 0, 0, 0);
        __syncthreads();                   // next tile staged; this buf free
    }
}

// -------------------------- 64x128 GEMM core, double-buffered prefetch (R17)
// As 2*64*32, Bs 2*128*32. 4 waves as 2x2; each wave 32 rows x 64 cols.
__device__ __forceinline__ void gemm64_core(
    const bf16* __restrict__ A, const bf16* __restrict__ Bt, const int Kd,
    const int m0, const int n0, bf16* As, bf16* Bs, f32x4 acc[2][4])
{
    const int tid  = threadIdx.x;
    const int lane = tid & 63;
    const int wave = tid >> 6;
    const int wr   = (wave >> 1) * 32;
    const int wc   = (wave & 1) * 64;
    const int lr   = lane & 15;
    const int q4   = lane >> 4;

#pragma unroll
    for (int i = 0; i < 2; ++i)
#pragma unroll
        for (int j = 0; j < 4; ++j) {
            acc[i][j][0] = 0.f; acc[i][j][1] = 0.f; acc[i][j][2] = 0.f; acc[i][j][3] = 0.f;
        }

    auto stage = [&](int buf, int k0) {
        {   // A tile 64x32: 256 chunks, one per thread
            const int chunk = tid;
            const int row   = chunk >> 2;
            const int cg    = (chunk & 3) * 8;
            async_copy16(As + buf * 2048 + (wave * 64) * 8, A + (size_t)(m0 + row) * Kd + k0 + cg);
        }
#pragma unroll
        for (int it = 0; it < 2; ++it) {   // B tile 128x32: 512 chunks
            const int cb0   = (it * 4 + wave) * 64;
            const int chunk = cb0 + lane;
            const int row   = chunk >> 2;
            const int cg    = (chunk & 3) * 8;
            async_copy16(Bs + buf * 4096 + cb0 * 8, Bt + (size_t)(n0 + row) * Kd + k0 + cg);
        }
    };

    const int NT = Kd >> 5;
    stage(0, 0);
    __syncthreads();

    for (int t = 0; t < NT; ++t) {
        const int buf = t & 1;
        if (t + 1 < NT) stage(buf ^ 1, (t + 1) * 32);

        const bf16* Ab = As + buf * 2048;
        const bf16* Bb = Bs + buf * 4096;
        bf16x8 af[2], bfr[4];
#pragma unroll
        for (int rb = 0; rb < 2; ++rb)
            af[rb] = *(const bf16x8*)&Ab[(wr + rb * 16 + lr) * 32 + q4 * 8];
#pragma unroll
        for (int cb = 0; cb < 4; ++cb)
            bfr[cb] = *(const bf16x8*)&Bb[(wc + cb * 16 + lr) * 32 + q4 * 8];
#pragma unroll
        for (int rb = 0; rb < 2; ++rb)
#pragma unroll
            for (int cb = 0; cb < 4; ++cb)
                acc[rb][cb] = __builtin_amdgcn_mfma_f32_16x16x32_bf16(af[rb], bfr[cb], acc[rb][cb], 0, 0, 0);
        __syncthreads();
    }
}

// -------------------------------------------------- merged prep (all inputs)
// 13312 blocks: [0,3072) Wqkv T; [3072,4096) Wr T; [4096,5120) Wo T;
// [5120,9216) cast_cat(mem,inputs); [9216,13312) cast(r).
__global__ __launch_bounds__(256) void k_prep(
    const float* __restrict__ Wqkv, const float* __restrict__ Wr,
    const float* __restrict__ Wo,
    const float* __restrict__ mem, const float* __restrict__ inp,
    const float* __restrict__ r,
    bf16* __restrict__ Wqkvt, bf16* __restrict__ Wrt, bf16* __restrict__ Wot,
    bf16* __restrict__ catb, bf16* __restrict__ rb)
{
    __shared__ float t[32][33];
    int id = blockIdx.x;
    if (id < 5120) {                       // ---- weight transpose+cast
        const float* in; bf16* out; int C, bx, by;
        if (id < 3072)      { in = Wqkv; out = Wqkvt; C = 3072; bx = id % 96; by = id / 96; }
        else if (id < 4096) { id -= 3072; in = Wr; out = Wrt; C = 1024; bx = id & 31; by = id >> 5; }
        else                { id -= 4096; in = Wo; out = Wot; C = 1024; bx = id & 31; by = id >> 5; }
        const int R = 1024;
        const int c0 = bx * 32, r0 = by * 32;
        const int lc = threadIdx.x & 31, lrow = threadIdx.x >> 5;
#pragma unroll
        for (int p = 0; p < 4; ++p)
            t[lrow + p * 8][lc] = in[(size_t)(r0 + lrow + p * 8) * C + c0 + lc];
        __syncthreads();
#pragma unroll
        for (int p = 0; p < 4; ++p)
            out[(size_t)(c0 + lrow + p * 8) * R + r0 + lc] = (bf16)t[lc][lrow + p * 8];
    } else if (id < 9216) {                // ---- cast_cat(mem, inputs)
        const int e   = ((id - 5120) * 256 + threadIdx.x) * 4;
        const int row = e >> 10, dc = e & 1023;
        const int b   = row >> 11, k = row & 2047;
        const float* src = (k < 1024) ? mem + ((size_t)b * 1024 + k) * 1024 + dc
                                      : inp + ((size_t)b * 1024 + (k - 1024)) * 1024 + dc;
        float4 f = *(const float4*)src;
        bf16x4 o; o[0] = (bf16)f.x; o[1] = (bf16)f.y; o[2] = (bf16)f.z; o[3] = (bf16)f.w;
        *(bf16x4*)&catb[e] = o;
    } else {                               // ---- cast(r)
        const int e = ((id - 9216) * 256 + threadIdx.x) * 4;
        float4 f = *(const float4*)(r + e);
        bf16x4 o; o[0] = (bf16)f.x; o[1] = (bf16)f.y; o[2] = (bf16)f.z; o[3] = (bf16)f.w;
        *(bf16x4*)&rb[e] = o;
    }
}

// ------------------------------------------------- fused KV + Q + R GEMM
// grid (32, 28): y<16 KV-part; y in [16,20) Q-part (linear remap, input rows
// only); y in [20,28) R GEMM.
__global__ __launch_bounds__(256) void k_gemm_qkvr(
    const bf16* __restrict__ catb, const bf16* __restrict__ Wqkvt,
    const float* __restrict__ b_qkv, const float* __restrict__ u, const float* __restrict__ v,
    const bf16* __restrict__ rb_, const bf16* __restrict__ Wrt,
    const float* __restrict__ b_r,
    bf16* __restrict__ hq_u, bf16* __restrict__ hq_v,
    bf16* __restrict__ hk, bf16* __restrict__ hvT, bf16* __restrict__ hr)
{
    __shared__ bf16 lds[4 * 128 * 32];     // dbuf: As 2*4096, Bs 2*4096
    f32x4 acc[4][4];
    const int lane = threadIdx.x & 63, wave = threadIdx.x >> 6;
    const int wr = (wave >> 1) * 64, wc = (wave & 1) * 64;
    const int lr = lane & 15, q4 = lane >> 4;
    const int y = blockIdx.y;

    if (y < 16) {                       // ---- KV part
        const int m0 = blockIdx.x * 128;
        const int n0 = 1024 + y * 128;
        gemm128_core(catb, Wqkvt, 1024, m0, n0, lds, lds + 2 * 4096, acc);
#pragma unroll
        for (int rb = 0; rb < 4; ++rb) {
#pragma unroll
            for (int cb = 0; cb < 4; ++cb) {
                const int col  = n0 + wc + cb * 16 + lr;
                const int part = col >> 10;             // 1 or 2
                const int hd   = col & 1023;
                const int h    = hd >> 6, d = hd & 63;
                const float bcol = b_qkv[col];
#pragma unroll
                for (int r = 0; r < 4; ++r) {
                    const int row = m0 + wr + rb * 16 + q4 * 4 + r;
                    const int b   = row >> 11, k = row & 2047;
                    const float val = acc[rb][cb][r] + bcol;
                    if (part == 1) {
                        hvT[(((size_t)(b * 16 + h)) * 64 + d) * 2048 + k] = (bf16)val;
                    } else {
                        hk[(((size_t)(b * 16 + h)) * 2048 + k) * 64 + d] = (bf16)val;
                    }
                }
            }
        }
    } else if (y < 20) {                // ---- Q part (input rows only)
        const int linear = (y - 16) * 32 + blockIdx.x;   // [0,128)
        const int n0 = (linear & 7) * 128;
        const int mi = linear >> 3;                       // [0,16)
        const int m0 = (mi >> 3) * 2048 + 1024 + (mi & 7) * 128;
        gemm128_core(catb, Wqkvt, 1024, m0, n0, lds, lds + 2 * 4096, acc);
#pragma unroll
        for (int rb = 0; rb < 4; ++rb) {
#pragma unroll
            for (int cb = 0; cb < 4; ++cb) {
                const int col = n0 + wc + cb * 16 + lr;   // [0,1024)
                const int h = col >> 6, d = col & 63;
                const float bcol = b_qkv[col];
                const float uc = u[col], vc = v[col];
#pragma unroll
                for (int r = 0; r < 4; ++r) {
                    const int row = m0 + wr + rb * 16 + q4 * 4 + r;
                    const int b   = row >> 11, k = row & 2047;   // k in [1024,2048)
                    const float val = acc[rb][cb][r] + bcol;
                    const size_t o = (((size_t)(b * 16 + h)) * 1024 + (k - 1024)) * 64 + d;
                    hq_u[o] = (bf16)(val + uc);
                    hq_v[o] = (bf16)(val + vc);
                }
            }
        }
    } else {                            // ---- R GEMM
        const int m0 = blockIdx.x * 128;
        const int n0 = (y - 20) * 128;
        gemm128_core(rb_, Wrt, 1024, m0, n0, lds, lds + 2 * 4096, acc);
#pragma unroll
        for (int rb = 0; rb < 4; ++rb) {
#pragma unroll
            for (int cb = 0; cb < 4; ++cb) {
                const int col = n0 + wc + cb * 16 + lr;
                const int h = col >> 6, d = col & 63;
                const float bcol = b_r[col];
#pragma unroll
                for (int r = 0; r < 4; ++r) {
                    const int row = m0 + wr + rb * 16 + q4 * 4 + r;
                    const int b = row >> 11, k = row & 2047;
                    hr[(((size_t)(b * 16 + h)) * 2048 + k) * 64 + d] = (bf16)(acc[rb][cb][r] + bcol);
                }
            }
        }
    }
}

// -------------------------------------------------- out GEMM (64x128 tiles)
__global__ __launch_bounds__(256) void k_gemm_out(
    const bf16* __restrict__ attn, const bf16* __restrict__ Wt,
    const float* __restrict__ bias, float* __restrict__ out)
{
    __shared__ bf16 lds[2 * 2048 + 2 * 4096];
    f32x4 acc[2][4];
    const int m0 = blockIdx.x * 64, n0 = blockIdx.y * 128;
    gemm64_core(attn, Wt, 1024, m0, n0, lds, lds + 2 * 2048, acc);

    const int lane = threadIdx.x & 63, wave = threadIdx.x >> 6;
    const int wr = (wave >> 1) * 32, wc = (wave & 1) * 64;
    const int lr = lane & 15, q4 = lane >> 4;
#pragma unroll
    for (int rb = 0; rb < 2; ++rb) {
#pragma unroll
        for (int cb = 0; cb < 4; ++cb) {
            const int col = n0 + wc + cb * 16 + lr;
            const float bcol = bias[col];
#pragma unroll
            for (int r = 0; r < 4; ++r) {
                const int row = m0 + wr + rb * 16 + q4 * 4 + r;
                out[(size_t)row * 1024 + col] = acc[rb][cb][r] + bcol;
            }
        }
    }
}

// -------------------------------------- fused attention (R16, unchanged)
__global__ __launch_bounds__(256) void k_attn(
    const bf16* __restrict__ hq_u, const bf16* __restrict__ hq_v,
    const bf16* __restrict__ hk, const bf16* __restrict__ hvT,
    const bf16* __restrict__ hr, bf16* __restrict__ attn)
{
    __shared__ bf16 Ks[2][64][72];     // K tile [k][d], double-buffered
    __shared__ bf16 Vt[2][64][72];     // V tile [d][k], double-buffered
    __shared__ bf16 Rs[192 * 72];      // R rolling window: 3 slots x 64 rows
    __shared__ bf16 U[4][1600];        // per-wave: BDT [80][20] / Ps [16][76]

    const int bh = blockIdx.y;
    const int qt = (bh & 16) ? (15 - (int)blockIdx.x) : (int)blockIdx.x;
    const int q0 = qt * 64;
    const int tid = threadIdx.x, lane = tid & 63, wave = tid >> 6;
    const int lr = lane & 15, q4 = lane >> 4;
    bf16* Uw = &U[wave][0];

    const int nt  = 17 + qt;
    const int m0c = 15 - qt;
    const size_t kvbase = (size_t)bh * 2048 * 64;

    const int ci0  = tid,        r0_ = ci0 >> 3,  c0_ = (ci0 & 7) * 8;
    const int ci1  = 256 + tid,  r1_ = ci1 >> 3,  c1_ = (ci1 & 7) * 8;

    bf16x8 kv0, kv1, vv0, vv1, rv0, rv1;
    auto load_kv = [&](int t) {
        const int k0 = t * 64;
        kv0 = *(const bf16x8*)&hk [kvbase + (size_t)(k0 + r0_) * 64 + c0_];
        kv1 = *(const bf16x8*)&hk [kvbase + (size_t)(k0 + r1_) * 64 + c1_];
        vv0 = *(const bf16x8*)&hvT[kvbase + (size_t)r0_ * 2048 + k0 + c0_];
        vv1 = *(const bf16x8*)&hvT[kvbase + (size_t)r1_ * 2048 + k0 + c1_];
    };
    auto load_r = [&](int c) {
        if (c * 64 < 2048) {
            rv0 = *(const bf16x8*)&hr[kvbase + (size_t)(c * 64 + r0_) * 64 + c0_];
            rv1 = *(const bf16x8*)&hr[kvbase + (size_t)(c * 64 + r1_) * 64 + c1_];
        } else {
#pragma unroll
            for (int z = 0; z < 8; ++z) { rv0[z] = (bf16)0.f; rv1[z] = (bf16)0.f; }
        }
    };
    auto write_kv = [&](int buf) {
        *(bf16x8*)&Ks[buf][r0_][c0_] = kv0;
        *(bf16x8*)&Ks[buf][r1_][c1_] = kv1;
        *(bf16x8*)&Vt[buf][r0_][c0_] = vv0;
        *(bf16x8*)&Vt[buf][r1_][c1_] = vv1;
    };
    auto write_r = [&](int slot) {
        *(bf16x8*)&Rs[(slot * 64 + r0_) * 72 + c0_] = rv0;
        *(bf16x8*)&Rs[(slot * 64 + r1_) * 72 + c1_] = rv1;
    };

    const size_t qrow = ((size_t)bh * 1024 + q0 + wave * 16 + lr) * 64;
    const bf16x8 qu0 = *(const bf16x8*)&hq_u[qrow + q4 * 8];
    const bf16x8 qu1 = *(const bf16x8*)&hq_u[qrow + 32 + q4 * 8];
    const bf16x8 qv0 = *(const bf16x8*)&hq_v[qrow + q4 * 8];
    const bf16x8 qv1 = *(const bf16x8*)&hq_v[qrow + 32 + q4 * 8];

    f32x4 Oacc[4];
#pragma unroll
    for (int i = 0; i < 4; ++i) { Oacc[i][0] = 0.f; Oacc[i][1] = 0.f; Oacc[i][2] = 0.f; Oacc[i][3] = 0.f; }
    float lp[4] = {0.f, 0.f, 0.f, 0.f};

    load_kv(0);  write_kv(0);
    load_r(m0c);     write_r(m0c % 3);
    load_r(m0c + 1); write_r((m0c + 1) % 3);
    __syncthreads();

    for (int t = 0; t < nt; ++t) {
        const int k0  = t * 64;
        const int mt  = m0c + t;
        const int s0  = mt % 3;
        const int s1  = (s0 + 1 == 3) ? 0 : s0 + 1;
        const int s2  = (s1 + 1 == 3) ? 0 : s1 + 1;
        const int buf = t & 1;
        const bool more = (t + 1 < nt);
        if (more) { load_kv(t + 1); load_r(mt + 2); }

        __builtin_amdgcn_s_setprio(1);
        // ---- AC = (hq+u) @ K^T
        f32x4 S[4];
#pragma unroll
        for (int cb = 0; cb < 4; ++cb) {
            const bf16x8 kf0 = *(const bf16x8*)&Ks[buf][cb * 16 + lr][q4 * 8];
            const bf16x8 kf1 = *(const bf16x8*)&Ks[buf][cb * 16 + lr][32 + q4 * 8];
            f32x4 z; z[0] = 0.f; z[1] = 0.f; z[2] = 0.f; z[3] = 0.f;
            z = __builtin_amdgcn_mfma_f32_16x16x32_bf16(qu0, kf0, z, 0, 0, 0);
            S[cb] = __builtin_amdgcn_mfma_f32_16x16x32_bf16(qu1, kf1, z, 0, 0, 0);
        }
        // ---- BD band -> transposed BDT view (stride 20), b64 writes
#pragma unroll
        for (int jbi = 0; jbi < 5; ++jbi) {
            const int jb   = jbi + 3 - wave;
            const int rrow = ((jb & 4) ? s1 : s0) * 64 + (jb & 3) * 16 + lr;
            const bf16x8 rf0 = *(const bf16x8*)&Rs[rrow * 72 + q4 * 8];
            const bf16x8 rf1 = *(const bf16x8*)&Rs[rrow * 72 + 32 + q4 * 8];
            f32x4 z; z[0] = 0.f; z[1] = 0.f; z[2] = 0.f; z[3] = 0.f;
            z = __builtin_amdgcn_mfma_f32_16x16x32_bf16(qv0, rf0, z, 0, 0, 0);
            z = __builtin_amdgcn_mfma_f32_16x16x32_bf16(qv1, rf1, z, 0, 0, 0);
            bf16x4 pk;
            pk[0] = (bf16)z[0]; pk[1] = (bf16)z[1]; pk[2] = (bf16)z[2]; pk[3] = (bf16)z[3];
            *(bf16x4*)&Uw[(jbi * 16 + lr) * 20 + q4 * 4] = pk;
        }

        // ---- shifted BD reads into registers (before Ps writes)
        float bdv[4][4];
#pragma unroll
        for (int cb = 0; cb < 4; ++cb)
#pragma unroll
            for (int r = 0; r < 4; ++r) {
                const int tq = q4 * 4 + r;
                bdv[cb][r] = (float)Uw[(cb * 16 + lr + 15 - tq) * 20 + tq];
            }

        // ---- scores: mask, exp, accumulate l, Ps write (stride 76)
#pragma unroll
        for (int cb = 0; cb < 4; ++cb) {
            const int k = k0 + cb * 16 + lr;
#pragma unroll
            for (int r = 0; r < 4; ++r) {
                const int q = q0 + wave * 16 + q4 * 4 + r;
                const float s = (S[cb][r] + bdv[cb][r]) * 0.125f;
                const float p = (k <= 1024 + q) ? __expf(s) : 0.f;
                lp[r] += p;
                Uw[(q4 * 4 + r) * 76 + cb * 16 + lr] = (bf16)p;
            }
        }

        // ---- PV
        const bf16x8 pf0 = *(const bf16x8*)&Uw[lr * 76 + q4 * 8];
        const bf16x8 pf1 = *(const bf16x8*)&Uw[lr * 76 + 32 + q4 * 8];
#pragma unroll
        for (int db = 0; db < 4; ++db) {
            const bf16x8 vf0 = *(const bf16x8*)&Vt[buf][db * 16 + lr][q4 * 8];
            const bf16x8 vf1 = *(const bf16x8*)&Vt[buf][db * 16 + lr][32 + q4 * 8];
            Oacc[db] = __builtin_amdgcn_mfma_f32_16x16x32_bf16(pf0, vf0, Oacc[db], 0, 0, 0);
            Oacc[db] = __builtin_amdgcn_mfma_f32_16x16x32_bf16(pf1, vf1, Oacc[db], 0, 0, 0);
        }
        __builtin_amdgcn_s_setprio(0);

        if (more) {
            write_kv(buf ^ 1);
            write_r(s2);
            __syncthreads();
        }
    }

    // ---- 16-lane row-sum of l, normalize, write
#pragma unroll
    for (int off = 1; off < 16; off <<= 1)
#pragma unroll
        for (int r = 0; r < 4; ++r) lp[r] += __shfl_xor(lp[r], off, 64);

    const int b = bh >> 4, h = bh & 15;
#pragma unroll
    for (int r = 0; r < 4; ++r) {
        const float rl = 1.f / lp[r];
        const int q = q0 + wave * 16 + q4 * 4 + r;
#pragma unroll
        for (int db = 0; db < 4; ++db) {
            const int d = db * 16 + lr;
            attn[(((size_t)b * 1024 + q) * 16 + h) * 64 + d] = (bf16)(Oacc[db][r] * rl);
        }
    }
}

// ------------------------------------------------------------------ launch
extern "C" void kernel_launch(void* const* d_in, const int* in_sizes, int n_in,
                              void* d_out, int out_size, void* d_ws, size_t ws_size,
                              hipStream_t stream)
{
    const float* inputs = (const float*)d_in[0];
    const float* mem    = (const float*)d_in[1];
    const float* r      = (const float*)d_in[2];
    const float* W_qkv  = (const float*)d_in[3];
    const float* b_qkv  = (const float*)d_in[4];
    const float* W_r    = (const float*)d_in[5];
    const float* b_r    = (const float*)d_in[6];
    const float* W_o    = (const float*)d_in[7];
    const float* b_o    = (const float*)d_in[8];
    const float* u      = (const float*)d_in[9];
    const float* v      = (const float*)d_in[10];
    float* out = (float*)d_out;

    char* ws = (char*)d_ws;
    size_t off = 0;
    auto alloc = [&](size_t bytes) -> void* {
        void* p = ws + off;
        off += (bytes + 255) & ~(size_t)255;
        return p;
    };
    bf16* hq_u  = (bf16*)alloc(2ull * 16 * 1024 * 64 * 2);
    bf16* hq_v  = (bf16*)alloc(2ull * 16 * 1024 * 64 * 2);
    bf16* hk    = (bf16*)alloc(2ull * 16 * 2048 * 64 * 2);
    bf16* hvT   = (bf16*)alloc(2ull * 16 * 2048 * 64 * 2);
    bf16* hr    = (bf16*)alloc(2ull * 16 * 2048 * 64 * 2);
    bf16* attnb = (bf16*)alloc(2ull * 1024 * 1024 * 2);
    bf16* Wot   = (bf16*)alloc(1024ull * 1024 * 2);
    bf16* catb  = (bf16*)alloc(4096ull * 1024 * 2);
    bf16* rb    = (bf16*)alloc(4096ull * 1024 * 2);
    bf16* Wqkvt = (bf16*)alloc(3072ull * 1024 * 2);
    bf16* Wrt   = (bf16*)alloc(1024ull * 1024 * 2);

    k_prep<<<13312, 256, 0, stream>>>(W_qkv, W_r, W_o, mem, inputs, r,
                                      Wqkvt, Wrt, Wot, catb, rb);

    k_gemm_qkvr<<<dim3(32, 28), 256, 0, stream>>>(catb, Wqkvt, b_qkv, u, v,
                                                  rb, Wrt, b_r,
                                                  hq_u, hq_v, hk, hvT, hr);
    k_attn<<<dim3(16, 32), 256, 0, stream>>>(hq_u, hq_v, hk, hvT, hr, attnb);
    k_gemm_out<<<dim3(32, 8), 256, 0, stream>>>(attnb, Wot, b_o, out);
}

// Round 10
// 244.006 us; speedup vs baseline: 1.3903x; 1.0196x over previous
//
#include <hip/hip_runtime.h>
#include <hip/hip_bf16.h>
#include <stdint.h>

// Transformer-XL relative MHA on MI355X (gfx950), bf16 MFMA pipeline.
// B=2, Q=1024, M=1024, D=1024, H=16, DH=64, K=2048.
// Evidence log:
//  - R5 failure isolated to bpermute block-selection (banned).
//  - R12: qt complement-remap; setprio; dead-tail skip. 305->287.
//  - R13: rolling R window + single barrier + fused qkvr GEMM. 287->272.
//  - R14 REFUTED (153 us): register-direct K/V/R = per-lane gathers. LDS
//    staging is a gather->coalesce converter. Reverted.
//  - R15: BDT b64 writes + merged preps. 272->261.7.
//  - R16: QKV split (-4.3 GFLOP) + 64x128 out GEMM. 261.7->249.9.
//  - R17 NEUTRAL (248.8): GEMM dbuf+prefetch ~= m99/m100 null (TLP already
//    hides staging latency at 4 blocks/CU). Kept (harmless).
//  - R18 (this): k_attn staging via global_load_lds (removes 6 wave-issued
//    b128 LDS writes + 6 VMEM reg round-trips per wave-iter; LDS-issue model
//    says ~12-15%). Requires linear LDS dest => padding dropped to [64][64];
//    bank conflicts handled by producer-side swizzle (qkvr writes hk/hvT/hr
//    with d ^= (k&7)<<3 inside the 64-col tile; free - writes were already
//    scattered) + XOR on attn fragment-read cols (col ^ (lr&7)<<3; 2-way =
//    free). Stale R rows (j>=2048, was zero-filled) reach only masked k
//    (j=1023+k-q>=2048 <=> masked); select kills NaN. LDS 77312->70144 B.

typedef __bf16 bf16;
typedef __bf16 bf16x2 __attribute__((ext_vector_type(2)));
typedef __bf16 bf16x4 __attribute__((ext_vector_type(4)));
typedef __bf16 bf16x8 __attribute__((ext_vector_type(8)));
typedef float  f32x4  __attribute__((ext_vector_type(4)));

// ---------------------------------------------------------------- async copy
__device__ __forceinline__ void async_copy16(void* lds, const void* g) {
    auto gp = (const __attribute__((address_space(1))) void*)(uintptr_t)g;
    auto lp = (__attribute__((address_space(3))) void*)(uint32_t)(uintptr_t)lds;
    __builtin_amdgcn_global_load_lds(gp, lp, 16, 0, 0);
}

// ------------------------- 128x128 GEMM core, double-buffered prefetch (R17)
__device__ __forceinline__ void gemm128_core(
    const bf16* __restrict__ A, const bf16* __restrict__ Bt, const int Kd,
    const int m0, const int n0, bf16* As, bf16* Bs, f32x4 acc[4][4])
{
    const int tid  = threadIdx.x;
    const int lane = tid & 63;
    const int wave = tid >> 6;
    const int wr   = (wave >> 1) * 64;
    const int wc   = (wave & 1) * 64;
    const int lr   = lane & 15;
    const int q4   = lane >> 4;

#pragma unroll
    for (int i = 0; i < 4; ++i)
#pragma unroll
        for (int j = 0; j < 4; ++j) {
            acc[i][j][0] = 0.f; acc[i][j][1] = 0.f; acc[i][j][2] = 0.f; acc[i][j][3] = 0.f;
        }

    auto stage = [&](int buf, int k0) {
#pragma unroll
        for (int it = 0; it < 2; ++it) {
            const int cb0   = (it * 4 + wave) * 64;   // wave-uniform chunk base
            const int chunk = cb0 + lane;
            const int row   = chunk >> 2;
            const int cg    = (chunk & 3) * 8;
            async_copy16(As + buf * 4096 + cb0 * 8, A  + (size_t)(m0 + row) * Kd + k0 + cg);
            async_copy16(Bs + buf * 4096 + cb0 * 8, Bt + (size_t)(n0 + row) * Kd + k0 + cg);
        }
    };

    const int NT = Kd >> 5;
    stage(0, 0);
    __syncthreads();                       // tile 0 staged

    for (int t = 0; t < NT; ++t) {
        const int buf = t & 1;
        if (t + 1 < NT) stage(buf ^ 1, (t + 1) * 32);   // prefetch next step

        const bf16* Ab = As + buf * 4096;
        const bf16* Bb = Bs + buf * 4096;
        bf16x8 af[4], bfr[4];
#pragma unroll
        for (int rb = 0; rb < 4; ++rb)
            af[rb] = *(const bf16x8*)&Ab[(wr + rb * 16 + lr) * 32 + q4 * 8];
#pragma unroll
        for (int cb = 0; cb < 4; ++cb)
            bfr[cb] = *(const bf16x8*)&Bb[(wc + cb * 16 + lr) * 32 + q4 * 8];
#pragma unroll
        for (int rb = 0; rb < 4; ++rb)
#pragma unroll
            for (int cb = 0; cb < 4; ++cb)
                acc[rb][cb] = __builtin_amdgcn_mfma_f32_16x16x32_bf16(af[rb], bfr[cb], acc[rb][cb], 0, 0, 0);
        __syncthreads();                   // next tile staged; this buf free
    }
}

// -------------------------- 64x128 GEMM core, double-buffered prefetch (R17)
__device__ __forceinline__ void gemm64_core(
    const bf16* __restrict__ A, const bf16* __restrict__ Bt, const int Kd,
    const int m0, const int n0, bf16* As, bf16* Bs, f32x4 acc[2][4])
{
    const int tid  = threadIdx.x;
    const int lane = tid & 63;
    const int wave = tid >> 6;
    const int wr   = (wave >> 1) * 32;
    const int wc   = (wave & 1) * 64;
    const int lr   = lane & 15;
    const int q4   = lane >> 4;

#pragma unroll
    for (int i = 0; i < 2; ++i)
#pragma unroll
        for (int j = 0; j < 4; ++j) {
            acc[i][j][0] = 0.f; acc[i][j][1] = 0.f; acc[i][j][2] = 0.f; acc[i][j][3] = 0.f;
        }

    auto stage = [&](int buf, int k0) {
        {
            const int chunk = tid;
            const int row   = chunk >> 2;
            const int cg    = (chunk & 3) * 8;
            async_copy16(As + buf * 2048 + (wave * 64) * 8, A + (size_t)(m0 + row) * Kd + k0 + cg);
        }
#pragma unroll
        for (int it = 0; it < 2; ++it) {
            const int cb0   = (it * 4 + wave) * 64;
            const int chunk = cb0 + lane;
            const int row   = chunk >> 2;
            const int cg    = (chunk & 3) * 8;
            async_copy16(Bs + buf * 4096 + cb0 * 8, Bt + (size_t)(n0 + row) * Kd + k0 + cg);
        }
    };

    const int NT = Kd >> 5;
    stage(0, 0);
    __syncthreads();

    for (int t = 0; t < NT; ++t) {
        const int buf = t & 1;
        if (t + 1 < NT) stage(buf ^ 1, (t + 1) * 32);

        const bf16* Ab = As + buf * 2048;
        const bf16* Bb = Bs + buf * 4096;
        bf16x8 af[2], bfr[4];
#pragma unroll
        for (int rb = 0; rb < 2; ++rb)
            af[rb] = *(const bf16x8*)&Ab[(wr + rb * 16 + lr) * 32 + q4 * 8];
#pragma unroll
        for (int cb = 0; cb < 4; ++cb)
            bfr[cb] = *(const bf16x8*)&Bb[(wc + cb * 16 + lr) * 32 + q4 * 8];
#pragma unroll
        for (int rb = 0; rb < 2; ++rb)
#pragma unroll
            for (int cb = 0; cb < 4; ++cb)
                acc[rb][cb] = __builtin_amdgcn_mfma_f32_16x16x32_bf16(af[rb], bfr[cb], acc[rb][cb], 0, 0, 0);
        __syncthreads();
    }
}

// -------------------------------------------------- merged prep (all inputs)
__global__ __launch_bounds__(256) void k_prep(
    const float* __restrict__ Wqkv, const float* __restrict__ Wr,
    const float* __restrict__ Wo,
    const float* __restrict__ mem, const float* __restrict__ inp,
    const float* __restrict__ r,
    bf16* __restrict__ Wqkvt, bf16* __restrict__ Wrt, bf16* __restrict__ Wot,
    bf16* __restrict__ catb, bf16* __restrict__ rb)
{
    __shared__ float t[32][33];
    int id = blockIdx.x;
    if (id < 5120) {
        const float* in; bf16* out; int C, bx, by;
        if (id < 3072)      { in = Wqkv; out = Wqkvt; C = 3072; bx = id % 96; by = id / 96; }
        else if (id < 4096) { id -= 3072; in = Wr; out = Wrt; C = 1024; bx = id & 31; by = id >> 5; }
        else                { id -= 4096; in = Wo; out = Wot; C = 1024; bx = id & 31; by = id >> 5; }
        const int R = 1024;
        const int c0 = bx * 32, r0 = by * 32;
        const int lc = threadIdx.x & 31, lrow = threadIdx.x >> 5;
#pragma unroll
        for (int p = 0; p < 4; ++p)
            t[lrow + p * 8][lc] = in[(size_t)(r0 + lrow + p * 8) * C + c0 + lc];
        __syncthreads();
#pragma unroll
        for (int p = 0; p < 4; ++p)
            out[(size_t)(c0 + lrow + p * 8) * R + r0 + lc] = (bf16)t[lc][lrow + p * 8];
    } else if (id < 9216) {
        const int e   = ((id - 5120) * 256 + threadIdx.x) * 4;
        const int row = e >> 10, dc = e & 1023;
        const int b   = row >> 11, k = row & 2047;
        const float* src = (k < 1024) ? mem + ((size_t)b * 1024 + k) * 1024 + dc
                                      : inp + ((size_t)b * 1024 + (k - 1024)) * 1024 + dc;
        float4 f = *(const float4*)src;
        bf16x4 o; o[0] = (bf16)f.x; o[1] = (bf16)f.y; o[2] = (bf16)f.z; o[3] = (bf16)f.w;
        *(bf16x4*)&catb[e] = o;
    } else {
        const int e = ((id - 9216) * 256 + threadIdx.x) * 4;
        float4 f = *(const float4*)(r + e);
        bf16x4 o; o[0] = (bf16)f.x; o[1] = (bf16)f.y; o[2] = (bf16)f.z; o[3] = (bf16)f.w;
        *(bf16x4*)&rb[e] = o;
    }
}

// ------------------------------------------------- fused KV + Q + R GEMM
// R18: hk/hvT/hr written PRE-SWIZZLED for the attn LDS tiles:
//   hk/hr: element col d' = d ^ ((k&7)<<3)   (row = k within 64-row tile)
//   hvT:   element col k' = (k&~63) | ((k&63) ^ ((d&7)<<3))  (row = d)
__global__ __launch_bounds__(256) void k_gemm_qkvr(
    const bf16* __restrict__ catb, const bf16* __restrict__ Wqkvt,
    const float* __restrict__ b_qkv, const float* __restrict__ u, const float* __restrict__ v,
    const bf16* __restrict__ rb_, const bf16* __restrict__ Wrt,
    const float* __restrict__ b_r,
    bf16* __restrict__ hq_u, bf16* __restrict__ hq_v,
    bf16* __restrict__ hk, bf16* __restrict__ hvT, bf16* __restrict__ hr)
{
    __shared__ bf16 lds[4 * 128 * 32];
    f32x4 acc[4][4];
    const int lane = threadIdx.x & 63, wave = threadIdx.x >> 6;
    const int wr = (wave >> 1) * 64, wc = (wave & 1) * 64;
    const int lr = lane & 15, q4 = lane >> 4;
    const int y = blockIdx.y;

    if (y < 16) {                       // ---- KV part
        const int m0 = blockIdx.x * 128;
        const int n0 = 1024 + y * 128;
        gemm128_core(catb, Wqkvt, 1024, m0, n0, lds, lds + 2 * 4096, acc);
#pragma unroll
        for (int rb = 0; rb < 4; ++rb) {
#pragma unroll
            for (int cb = 0; cb < 4; ++cb) {
                const int col  = n0 + wc + cb * 16 + lr;
                const int part = col >> 10;             // 1 or 2
                const int hd   = col & 1023;
                const int h    = hd >> 6, d = hd & 63;
                const float bcol = b_qkv[col];
#pragma unroll
                for (int r = 0; r < 4; ++r) {
                    const int row = m0 + wr + rb * 16 + q4 * 4 + r;
                    const int b   = row >> 11, k = row & 2047;
                    const float val = acc[rb][cb][r] + bcol;
                    if (part == 1) {
                        const int ks = (k & ~63) | ((k & 63) ^ ((d & 7) << 3));
                        hvT[(((size_t)(b * 16 + h)) * 64 + d) * 2048 + ks] = (bf16)val;
                    } else {
                        const int ds = d ^ ((k & 7) << 3);
                        hk[(((size_t)(b * 16 + h)) * 2048 + k) * 64 + ds] = (bf16)val;
                    }
                }
            }
        }
    } else if (y < 20) {                // ---- Q part (input rows only)
        const int linear = (y - 16) * 32 + blockIdx.x;   // [0,128)
        const int n0 = (linear & 7) * 128;
        const int mi = linear >> 3;                       // [0,16)
        const int m0 = (mi >> 3) * 2048 + 1024 + (mi & 7) * 128;
        gemm128_core(catb, Wqkvt, 1024, m0, n0, lds, lds + 2 * 4096, acc);
#pragma unroll
        for (int rb = 0; rb < 4; ++rb) {
#pragma unroll
            for (int cb = 0; cb < 4; ++cb) {
                const int col = n0 + wc + cb * 16 + lr;   // [0,1024)
                const int h = col >> 6, d = col & 63;
                const float bcol = b_qkv[col];
                const float uc = u[col], vc = v[col];
#pragma unroll
                for (int r = 0; r < 4; ++r) {
                    const int row = m0 + wr + rb * 16 + q4 * 4 + r;
                    const int b   = row >> 11, k = row & 2047;   // k in [1024,2048)
                    const float val = acc[rb][cb][r] + bcol;
                    const size_t o = (((size_t)(b * 16 + h)) * 1024 + (k - 1024)) * 64 + d;
                    hq_u[o] = (bf16)(val + uc);
                    hq_v[o] = (bf16)(val + vc);
                }
            }
        }
    } else {                            // ---- R GEMM
        const int m0 = blockIdx.x * 128;
        const int n0 = (y - 20) * 128;
        gemm128_core(rb_, Wrt, 1024, m0, n0, lds, lds + 2 * 4096, acc);
#pragma unroll
        for (int rb = 0; rb < 4; ++rb) {
#pragma unroll
            for (int cb = 0; cb < 4; ++cb) {
                const int col = n0 + wc + cb * 16 + lr;
                const int h = col >> 6, d = col & 63;
                const float bcol = b_r[col];
#pragma unroll
                for (int r = 0; r < 4; ++r) {
                    const int row = m0 + wr + rb * 16 + q4 * 4 + r;
                    const int b = row >> 11, k = row & 2047;
                    const int ds = d ^ ((k & 7) << 3);
                    hr[(((size_t)(b * 16 + h)) * 2048 + k) * 64 + ds] = (bf16)(acc[rb][cb][r] + bcol);
                }
            }
        }
    }
}

// -------------------------------------------------- out GEMM (64x128 tiles)
__global__ __launch_bounds__(256) void k_gemm_out(
    const bf16* __restrict__ attn, const bf16* __restrict__ Wt,
    const float* __restrict__ bias, float* __restrict__ out)
{
    __shared__ bf16 lds[2 * 2048 + 2 * 4096];
    f32x4 acc[2][4];
    const int m0 = blockIdx.x * 64, n0 = blockIdx.y * 128;
    gemm64_core(attn, Wt, 1024, m0, n0, lds, lds + 2 * 2048, acc);

    const int lane = threadIdx.x & 63, wave = threadIdx.x >> 6;
    const int wr = (wave >> 1) * 32, wc = (wave & 1) * 64;
    const int lr = lane & 15, q4 = lane >> 4;
#pragma unroll
    for (int rb = 0; rb < 2; ++rb) {
#pragma unroll
        for (int cb = 0; cb < 4; ++cb) {
            const int col = n0 + wc + cb * 16 + lr;
            const float bcol = bias[col];
#pragma unroll
            for (int r = 0; r < 4; ++r) {
                const int row = m0 + wr + rb * 16 + q4 * 4 + r;
                out[(size_t)row * 1024 + col] = acc[rb][cb][r] + bcol;
            }
        }
    }
}

// ---------------- fused attention (R18: global_load_lds staging, swizzled)
// Unpadded [64][64] tiles, linear LDS dest for async staging; fragment reads
// XOR-swizzled (col ^ (lr&7)<<3) to match producer-side swizzle. One barrier
// per tile (async writes target buf^1 / slot s2 - disjoint from reads; the
// barrier's vmcnt(0) drain completes staging). Stale R rows (j>=2048) only
// feed masked k. LDS: Ks 16384 + Vt 16384 + Rs 24576 + U 12800 = 70144 B.
__global__ __launch_bounds__(256) void k_attn(
    const bf16* __restrict__ hq_u, const bf16* __restrict__ hq_v,
    const bf16* __restrict__ hk, const bf16* __restrict__ hvT,
    const bf16* __restrict__ hr, bf16* __restrict__ attn)
{
    __shared__ bf16 Ks[2][64][64];     // K tile [k][d-swz], double-buffered
    __shared__ bf16 Vt[2][64][64];     // V tile [d][k-swz], double-buffered
    __shared__ bf16 Rs[192][64];       // R rolling window: 3 slots x 64 rows
    __shared__ bf16 U[4][1600];        // per-wave: BDT [80][20] / Ps [16][76]

    const int bh = blockIdx.y;
    const int qt = (bh & 16) ? (15 - (int)blockIdx.x) : (int)blockIdx.x;
    const int q0 = qt * 64;
    const int tid = threadIdx.x, lane = tid & 63, wave = tid >> 6;
    const int lr = lane & 15, q4 = lane >> 4;
    bf16* Uw = &U[wave][0];

    const int nt  = 17 + qt;
    const int m0c = 15 - qt;
    const size_t kvbase = (size_t)bh * 2048 * 64;

    // staging coordinates: chunk ci0=tid -> rows [0,32); ci1=256+tid -> [32,64)
    const int r0_ = tid >> 3, c0_ = (tid & 7) * 8;
    const int r1_ = 32 + r0_, c1_ = c0_;

    auto stage_kv = [&](int t, int buf) {
        const int k0 = t * 64;
        async_copy16(&Ks[buf][r0_][c0_], &hk [kvbase + (size_t)(k0 + r0_) * 64 + c0_]);
        async_copy16(&Ks[buf][r1_][c1_], &hk [kvbase + (size_t)(k0 + r1_) * 64 + c1_]);
        async_copy16(&Vt[buf][r0_][c0_], &hvT[kvbase + (size_t)r0_ * 2048 + k0 + c0_]);
        async_copy16(&Vt[buf][r1_][c1_], &hvT[kvbase + (size_t)r1_ * 2048 + k0 + c1_]);
    };
    auto stage_r = [&](int c, int slot) {   // R chunk c -> slot (skip OOB: stale ok, masked)
        if (c * 64 < 2048) {
            async_copy16(&Rs[slot * 64 + r0_][c0_], &hr[kvbase + (size_t)(c * 64 + r0_) * 64 + c0_]);
            async_copy16(&Rs[slot * 64 + r1_][c1_], &hr[kvbase + (size_t)(c * 64 + r1_) * 64 + c1_]);
        }
    };

    // Q fragments (A-operand layout: m = lane&15, k = (lane>>4)*8 + j)
    const size_t qrow = ((size_t)bh * 1024 + q0 + wave * 16 + lr) * 64;
    const bf16x8 qu0 = *(const bf16x8*)&hq_u[qrow + q4 * 8];
    const bf16x8 qu1 = *(const bf16x8*)&hq_u[qrow + 32 + q4 * 8];
    const bf16x8 qv0 = *(const bf16x8*)&hq_v[qrow + q4 * 8];
    const bf16x8 qv1 = *(const bf16x8*)&hq_v[qrow + 32 + q4 * 8];

    // swizzled fragment-read columns (match producer-side swizzle)
    const int sw  = (lr & 7) << 3;
    const int cA0 = (q4 * 8) ^ sw;
    const int cA1 = (32 + q4 * 8) ^ sw;

    f32x4 Oacc[4];
#pragma unroll
    for (int i = 0; i < 4; ++i) { Oacc[i][0] = 0.f; Oacc[i][1] = 0.f; Oacc[i][2] = 0.f; Oacc[i][3] = 0.f; }
    float lp[4] = {0.f, 0.f, 0.f, 0.f};

    // prologue: async-stage tile 0 + R chunks m0c, m0c+1; barrier drains vmcnt
    stage_kv(0, 0);
    stage_r(m0c,     m0c % 3);
    stage_r(m0c + 1, (m0c + 1) % 3);
    __syncthreads();

    for (int t = 0; t < nt; ++t) {
        const int k0  = t * 64;
        const int mt  = m0c + t;
        const int s0  = mt % 3;
        const int s1  = (s0 + 1 == 3) ? 0 : s0 + 1;
        const int s2  = (s1 + 1 == 3) ? 0 : s1 + 1;
        const int buf = t & 1;
        const bool more = (t + 1 < nt);
        // issue next tile's async staging NOW (targets disjoint regions)
        if (more) { stage_kv(t + 1, buf ^ 1); stage_r(mt + 2, s2); }

        __builtin_amdgcn_s_setprio(1);
        // ---- AC = (hq+u) @ K^T
        f32x4 S[4];
#pragma unroll
        for (int cb = 0; cb < 4; ++cb) {
            const bf16x8 kf0 = *(const bf16x8*)&Ks[buf][cb * 16 + lr][cA0];
            const bf16x8 kf1 = *(const bf16x8*)&Ks[buf][cb * 16 + lr][cA1];
            f32x4 z; z[0] = 0.f; z[1] = 0.f; z[2] = 0.f; z[3] = 0.f;
            z = __builtin_amdgcn_mfma_f32_16x16x32_bf16(qu0, kf0, z, 0, 0, 0);
            S[cb] = __builtin_amdgcn_mfma_f32_16x16x32_bf16(qu1, kf1, z, 0, 0, 0);
        }
        // ---- BD band -> transposed BDT view (stride 20), b64 writes
#pragma unroll
        for (int jbi = 0; jbi < 5; ++jbi) {
            const int jb   = jbi + 3 - wave;
            const int rrow = ((jb & 4) ? s1 : s0) * 64 + (jb & 3) * 16 + lr;
            const bf16x8 rf0 = *(const bf16x8*)&Rs[rrow][cA0];
            const bf16x8 rf1 = *(const bf16x8*)&Rs[rrow][cA1];
            f32x4 z; z[0] = 0.f; z[1] = 0.f; z[2] = 0.f; z[3] = 0.f;
            z = __builtin_amdgcn_mfma_f32_16x16x32_bf16(qv0, rf0, z, 0, 0, 0);
            z = __builtin_amdgcn_mfma_f32_16x16x32_bf16(qv1, rf1, z, 0, 0, 0);
            bf16x4 pk;
            pk[0] = (bf16)z[0]; pk[1] = (bf16)z[1]; pk[2] = (bf16)z[2]; pk[3] = (bf16)z[3];
            *(bf16x4*)&Uw[(jbi * 16 + lr) * 20 + q4 * 4] = pk;
        }

        // ---- shifted BD reads into registers (before Ps writes)
        float bdv[4][4];
#pragma unroll
        for (int cb = 0; cb < 4; ++cb)
#pragma unroll
            for (int r = 0; r < 4; ++r) {
                const int tq = q4 * 4 + r;
                bdv[cb][r] = (float)Uw[(cb * 16 + lr + 15 - tq) * 20 + tq];
            }

        // ---- scores: mask, exp, accumulate l, Ps write (stride 76)
#pragma unroll
        for (int cb = 0; cb < 4; ++cb) {
            const int k = k0 + cb * 16 + lr;
#pragma unroll
            for (int r = 0; r < 4; ++r) {
                const int q = q0 + wave * 16 + q4 * 4 + r;
                const float s = (S[cb][r] + bdv[cb][r]) * 0.125f;
                const float p = (k <= 1024 + q) ? __expf(s) : 0.f;
                lp[r] += p;
                Uw[(q4 * 4 + r) * 76 + cb * 16 + lr] = (bf16)p;
            }
        }

        // ---- PV
        const bf16x8 pf0 = *(const bf16x8*)&Uw[lr * 76 + q4 * 8];
        const bf16x8 pf1 = *(const bf16x8*)&Uw[lr * 76 + 32 + q4 * 8];
#pragma unroll
        for (int db = 0; db < 4; ++db) {
            const bf16x8 vf0 = *(const bf16x8*)&Vt[buf][db * 16 + lr][cA0];
            const bf16x8 vf1 = *(const bf16x8*)&Vt[buf][db * 16 + lr][cA1];
            Oacc[db] = __builtin_amdgcn_mfma_f32_16x16x32_bf16(pf0, vf0, Oacc[db], 0, 0, 0);
            Oacc[db] = __builtin_amdgcn_mfma_f32_16x16x32_bf16(pf1, vf1, Oacc[db], 0, 0, 0);
        }
        __builtin_amdgcn_s_setprio(0);

        if (more) __syncthreads();     // drains vmcnt -> staged tile visible
    }

    // ---- 16-lane row-sum of l, normalize, write
#pragma unroll
    for (int off = 1; off < 16; off <<= 1)
#pragma unroll
        for (int r = 0; r < 4; ++r) lp[r] += __shfl_xor(lp[r], off, 64);

    const int b = bh >> 4, h = bh & 15;
#pragma unroll
    for (int r = 0; r < 4; ++r) {
        const float rl = 1.f / lp[r];
        const int q = q0 + wave * 16 + q4 * 4 + r;
#pragma unroll
        for (int db = 0; db < 4; ++db) {
            const int d = db * 16 + lr;
            attn[(((size_t)b * 1024 + q) * 16 + h) * 64 + d] = (bf16)(Oacc[db][r] * rl);
        }
    }
}

// ------------------------------------------------------------------ launch
extern "C" void kernel_launch(void* const* d_in, const int* in_sizes, int n_in,
                              void* d_out, int out_size, void* d_ws, size_t ws_size,
                              hipStream_t stream)
{
    const float* inputs = (const float*)d_in[0];
    const float* mem    = (const float*)d_in[1];
    const float* r      = (const float*)d_in[2];
    const float* W_qkv  = (const float*)d_in[3];
    const float* b_qkv  = (const float*)d_in[4];
    const float* W_r    = (const float*)d_in[5];
    const float* b_r    = (const float*)d_in[6];
    const float* W_o    = (const float*)d_in[7];
    const float* b_o    = (const float*)d_in[8];
    const float* u      = (const float*)d_in[9];
    const float* v      = (const float*)d_in[10];
    float* out = (float*)d_out;

    char* ws = (char*)d_ws;
    size_t off = 0;
    auto alloc = [&](size_t bytes) -> void* {
        void* p = ws + off;
        off += (bytes + 255) & ~(size_t)255;
        return p;
    };
    bf16* hq_u  = (bf16*)alloc(2ull * 16 * 1024 * 64 * 2);
    bf16* hq_v  = (bf16*)alloc(2ull * 16 * 1024 * 64 * 2);
    bf16* hk    = (bf16*)alloc(2ull * 16 * 2048 * 64 * 2);
    bf16* hvT   = (bf16*)alloc(2ull * 16 * 2048 * 64 * 2);
    bf16* hr    = (bf16*)alloc(2ull * 16 * 2048 * 64 * 2);
    bf16* attnb = (bf16*)alloc(2ull * 1024 * 1024 * 2);
    bf16* Wot   = (bf16*)alloc(1024ull * 1024 * 2);
    bf16* catb  = (bf16*)alloc(4096ull * 1024 * 2);
    bf16* rb    = (bf16*)alloc(4096ull * 1024 * 2);
    bf16* Wqkvt = (bf16*)alloc(3072ull * 1024 * 2);
    bf16* Wrt   = (bf16*)alloc(1024ull * 1024 * 2);

    k_prep<<<13312, 256, 0, stream>>>(W_qkv, W_r, W_o, mem, inputs, r,
                                      Wqkvt, Wrt, Wot, catb, rb);

    k_gemm_qkvr<<<dim3(32, 28), 256, 0, stream>>>(catb, Wqkvt, b_qkv, u, v,
                                                  rb, Wrt, b_r,
                                                  hq_u, hq_v, hk, hvT, hr);
    k_attn<<<dim3(16, 32), 256, 0, stream>>>(hq_u, hq_v, hk, hvT, hr, attnb);
    k_gemm_out<<<dim3(32, 8), 256, 0, stream>>>(attnb, Wot, b_o, out);
}